// Round 16
// baseline (388.594 us; speedup 1.0000x reference)
//
#include <hip/hip_runtime.h>

static constexpr int N_ = 40000;
static constexpr int E_ = 1280000;
static constexpr int NS = N_ * 64;      // 2,560,000 scalar elems
static constexpr int NV = N_ * 48;      // 1,920,000 vector elems

typedef _Float16 half2_t __attribute__((ext_vector_type(2)));
typedef _Float16 half8_t __attribute__((ext_vector_type(8)));
typedef float float4_t __attribute__((ext_vector_type(4)));
typedef unsigned int uint;

__device__ __forceinline__ float silu_f(float x) { return __fdividef(x, 1.f + __expf(-x)); }
__device__ __forceinline__ int rfl(int x) { return __builtin_amdgcn_readfirstlane(x); }
__device__ __forceinline__ int xcc_id() {
    int x;
    asm volatile("s_getreg_b32 %0, hwreg(HW_REG_XCC_ID)" : "=s"(x));
    return x & 7;
}

// ============ fused front-end: rank(XCC-local copies) | convp | pack ==========
// r12/r14/r15 all ~358us total: rank's 1.28M device atomics are bound by
// SAME-ADDRESS CROSS-XCD line migration (~500cy each), which padding/batching
// can't fix. Fix: 8 counter copies, copy = executing XCD (s_getreg XCC_ID,
// guide m09) -> each copy's line is touched by ONE XCD only -> no migration,
// atomics at local-L2 rate. rnk packs (copy<<24 | rank-in-copy); scan1 emits
// per-node per-copy prefix pre8; place3 reconstructs the global slot.
// Within-row slot ORDER changes (still a bijection) -> gather sum reorder only.
__global__ __launch_bounds__(256) void k_front1(
    const int* __restrict__ eidx, int* __restrict__ cnt8, int* __restrict__ rnk,
    const float* __restrict__ scalars, const float* __restrict__ vectors,
    _Float16* __restrict__ sc16p, _Float16* __restrict__ vec16p,
    const float* __restrict__ W1, const float* __restrict__ Wa1,
    const float* __restrict__ W2, uint* __restrict__ tbl, uint* __restrict__ tbl2)
{
    int bid = blockIdx.x;
    if (bid < 1250) {
        // ---- rank: 4 edges/thread, XCC-local padded counter copies ----
        int c = xcc_id();
        int base = bid * 1024 + threadIdx.x;
#pragma unroll
        for (int k = 0; k < 4; k++) {
            int e = base + k * 256;
            int dst = eidx[E_ + e];
            int r = atomicAdd(&cnt8[((size_t)dst * 8 + c) * 16], 1);
            rnk[e] = (c << 24) | r;
        }
        return;
    }
    if (bid < 6250) {
        // ---- convp: f16 tables in MFMA order (round-7 proven) ----
        int t = (bid - 1250) * 256 + threadIdx.x;      // 5000*256 = N_*32 exactly
        if (t < N_ * 16) {
            int n = t >> 4, bl = t & 15;
            const float* srow = scalars + (size_t)n * 64;
            half2_t a, b;
            a.x = (_Float16)srow[bl];
            a.y = (_Float16)srow[16 + bl];
            b.x = (_Float16)srow[32 + bl];
            b.y = (_Float16)srow[48 + bl];
            uint2 u; u.x = __builtin_bit_cast(uint, a); u.y = __builtin_bit_cast(uint, b);
            *(uint2*)(sc16p + (size_t)n * 64 + bl * 4) = u;
        } else {
            int tt = t - N_ * 16;
            int n = tt >> 4, bl = tt & 15;
            const float* vrow = vectors + (size_t)n * 48 + bl * 3;
            half2_t a, b;
            a.x = (_Float16)vrow[0];
            a.y = (_Float16)vrow[1];
            b.x = (_Float16)vrow[2];
            b.y = (_Float16)0.f;
            uint2 u; u.x = __builtin_bit_cast(uint, a); u.y = __builtin_bit_cast(uint, b);
            *(uint2*)(vec16p + (size_t)n * 64 + bl * 4) = u;
        }
        return;
    }
    // ---- pack MFMA B tables: tbl = [Wa1_att|W1], tbl2 = W2 (12 blocks) ----
    int t = (bid - 6250) * 256 + threadIdx.x;          // [0, 3072)
    if (t < 1536) {
        int j = t >> 4, q = t & 15;
        int k0 = 2 * q, k1 = 2 * q + 1;
        float a = (j < 64) ? Wa1[(128 + k0) * 64 + j] : W1[k0 * 32 + (j - 64)];
        float b = (j < 64) ? Wa1[(128 + k1) * 64 + j] : W1[k1 * 32 + (j - 64)];
        half2_t v; v.x = (_Float16)a; v.y = (_Float16)b;
        tbl[t] = __builtin_bit_cast(uint, v);
    } else if (t < 3072) {
        int tt = t - 1536;
        int j = tt >> 4, q = tt & 15;
        half2_t v;
        v.x = (_Float16)W2[(2 * q + 0) * 96 + j];
        v.y = (_Float16)W2[(2 * q + 1) * 96 + j];
        tbl2[tt] = __builtin_bit_cast(uint, v);
    }
}

// ---- per-node attention precompute, wave-resident weights (r12 standalone) ----
static constexpr int PATT_BLOCKS = 512;              // 2048 waves
__global__ __launch_bounds__(256) void k_patt(
    const float* __restrict__ scalars, const float* __restrict__ Wa1,
    const float* __restrict__ ba1,
    _Float16* __restrict__ P1h, _Float16* __restrict__ P2h)
{
    int gw   = (blockIdx.x * 256 + threadIdx.x) >> 6;  // global wave id
    int lane = threadIdx.x & 63;
    float w[128];
#pragma unroll
    for (int k = 0; k < 128; k++) w[k] = Wa1[k * 64 + lane];
    float bias = ba1[lane];
    for (int n = gw; n < N_; n += PATT_BLOCKS * 4) {
        float sv = scalars[(size_t)n * 64 + lane];
        float a1 = bias, a2 = 0.f;
#pragma unroll
        for (int k = 0; k < 64; k++) {
            float sk = __shfl(sv, k, 64);
            a1 = fmaf(sk, w[k], a1);
            a2 = fmaf(sk, w[64 + k], a2);
        }
        P1h[(size_t)n * 64 + lane] = (_Float16)a1;
        P2h[(size_t)n * 64 + lane] = (_Float16)a2;
    }
}

// ====== scan1: per-node 8-copy prefix (pre8) + node total -> block scan =======
__global__ void k_scan1(const int* __restrict__ cnt8, int* __restrict__ pre8,
                        int* __restrict__ row_start, int* __restrict__ bsum)
{
    __shared__ int buf[1024];
    int b = blockIdx.x, tid = threadIdx.x;
    int idx = b * 1024 + tid;
    int v = 0;
    if (idx < N_) {
#pragma unroll
        for (int c = 0; c < 8; c++) {
            pre8[idx * 8 + c] = v;
            v += cnt8[((size_t)idx * 8 + c) * 16];
        }
    }
    buf[tid] = v;
    __syncthreads();
    for (int off = 1; off < 1024; off <<= 1) {
        int t = (tid >= off) ? buf[tid - off] : 0;
        __syncthreads();
        buf[tid] += t;
        __syncthreads();
    }
    if (idx < N_) row_start[idx] = buf[tid] - v;
    if (tid == 1023) bsum[b] = buf[1023];
}

// fused scan2+scan3: each block serially sums bsum[0..b-1] (<=40 ints)
__global__ void k_scan3(const int* __restrict__ bsum, int* __restrict__ row_start)
{
    __shared__ int boffs;
    if (threadIdx.x == 0) {
        int s = 0;
        for (int b = 0; b < (int)blockIdx.x; b++) s += bsum[b];
        boffs = s;
    }
    __syncthreads();
    int idx = blockIdx.x * 1024 + threadIdx.x;
    if (idx < N_) row_start[idx] += boffs;
    if (idx == N_) row_start[N_] = E_;
}

// place ONE 16B record per edge into sorted slot (round-12 proven store shape):
// slot = row_start[dst] + pre8[dst*8+c] + rank-in-copy.
__global__ void k_place3(const int* __restrict__ eidx, const float* __restrict__ edge_vec,
                         const int* __restrict__ row_start, const int* __restrict__ pre8,
                         const int* __restrict__ r, float4* __restrict__ rec)
{
    int e = blockIdx.x * 256 + threadIdx.x;
    int src = eidx[e];
    int dst = eidx[E_ + e];
    int rc = r[e];
    int c = rc >> 24, rr = rc & 0xffffff;
    size_t slot = (size_t)(row_start[dst] + pre8[dst * 8 + c] + rr);
    uint sd = (uint)src | ((uint)dst << 16);
    rec[slot] = make_float4(edge_vec[3 * e + 0], edge_vec[3 * e + 1],
                            edge_vec[3 * e + 2], __uint_as_float(sd));
}

// ================= edge phase: round-12 proven (split-phase, H-first, 52 VGPR) =
__global__ __launch_bounds__(256, 3) void k_edges_sorted(
    const float4* __restrict__ rec,
    const _Float16* __restrict__ P1h, const _Float16* __restrict__ P2h,
    const uint* __restrict__ tbl, const float* __restrict__ b1,
    const float* __restrict__ Wa2, const float* __restrict__ ba2,
    float4* __restrict__ attsh, int* __restrict__ srcbuf, uint* __restrict__ hbufp)
{
    __shared__ char lds_raw[4 * 8448];
    int tid = threadIdx.x;
    int wid = tid >> 6, lane = tid & 63;
    char* wbase = lds_raw + wid * 8448;
    int bl = lane & 15, bq = lane >> 4;

    int i = blockIdx.x * 256 + tid;        // i IS the sorted slot
    float4 ra = rec[(size_t)i];
    float ev0 = ra.x, ev1 = ra.y, ev2 = ra.z;
    uint sd = __float_as_uint(ra.w);
    int src = (int)(sd & 0xffffu);
    int dst = (int)(sd >> 16);

    float d = sqrtf(fmaf(ev0, ev0, fmaf(ev1, ev1, ev2 * ev2)));
    float inv_d = __fdividef(1.f, fmaxf(d, 1e-8f));
    float cut = (d < 10.f) ? 0.5f * (__cosf(0.31415927f * d) + 1.f) : 0.f;
    float cutd = cut * inv_d;
    float sh0 = ev1 * inv_d, sh1 = ev2 * inv_d, sh2 = ev0 * inv_d;

    // rbf via sin recurrence: sin((k+1)t) = 2cos(t)sin(kt) - sin((k-1)t)
    float th = 0.31415927f * d;
    float scur = __sinf(th);
    float twoC = 2.f * __cosf(th);
    float sprev = 0.f;
    uint rbf2[16];
#pragma unroll
    for (int q = 0; q < 16; q++) {
        float r0 = scur * cutd;
        float snext = fmaf(twoC, scur, -sprev);
        sprev = scur; scur = snext;
        float r1 = scur * cutd;
        snext = fmaf(twoC, scur, -sprev);
        sprev = scur; scur = snext;
        half2_t v; v.x = (_Float16)r0; v.y = (_Float16)r1;
        rbf2[q] = __builtin_bit_cast(uint, v);
    }
    {
        uint4* rw = (uint4*)(wbase + lane * 64);
        rw[0] = make_uint4(rbf2[0], rbf2[1], rbf2[2], rbf2[3]);
        rw[1] = make_uint4(rbf2[4], rbf2[5], rbf2[6], rbf2[7]);
        rw[2] = make_uint4(rbf2[8], rbf2[9], rbf2[10], rbf2[11]);
        rw[3] = make_uint4(rbf2[12], rbf2[13], rbf2[14], rbf2[15]);
    }
    uint4 bfr[6];
#pragma unroll
    for (int u = 0; u < 6; u++)
        bfr[u] = *(const uint4*)(tbl + (u * 16 + bl) * 16 + bq * 4);

    uint4 afr[4];
#pragma unroll
    for (int t = 0; t < 4; t++)
        afr[t] = *(const uint4*)(wbase + (t * 16 + bl) * 64 + bq * 16);

    _Float16* gtile = (_Float16*)wbase;

    // ---- phase H (FIRST): h filter cols 0..31 into stride-34 tile ----
#pragma unroll
    for (int t = 0; t < 4; t++) {
        half8_t av = __builtin_bit_cast(half8_t, afr[t]);
        int eb = t * 16 + bq * 4;
#pragma unroll
        for (int u = 4; u < 6; u++) {
            float4_t dd = __builtin_amdgcn_mfma_f32_16x16x32_f16(
                av, __builtin_bit_cast(half8_t, bfr[u]), (float4_t)(0.f), 0, 0, 0);
            int col = (u - 4) * 16 + bl;
            gtile[(eb + 0) * 34 + col] = (_Float16)dd[0];
            gtile[(eb + 1) * 34 + col] = (_Float16)dd[1];
            gtile[(eb + 2) * 34 + col] = (_Float16)dd[2];
            gtile[(eb + 3) * 34 + col] = (_Float16)dd[3];
        }
    }
    {
        const uint* growB = (const uint*)(wbase + (size_t)lane * 68);
        uint hp[16];
#pragma unroll
        for (int q = 0; q < 16; q++) {
            half2_t gg = __builtin_bit_cast(half2_t, growB[q]);
            half2_t v;
            v.x = (_Float16)silu_f((float)gg.x + b1[2 * q + 0]);
            v.y = (_Float16)silu_f((float)gg.y + b1[2 * q + 1]);
            hp[q] = __builtin_bit_cast(uint, v);
        }
        uint4* hrow4 = (uint4*)(hbufp + (size_t)i * 16);
#pragma unroll
        for (int q = 0; q < 4; q++)
            hrow4[q] = make_uint4(hp[4 * q + 0], hp[4 * q + 1], hp[4 * q + 2], hp[4 * q + 3]);
    }

    // ---- phase A: att filter cols 0..63 into stride-66 tile (same buffer) ----
    // afr/bfr have their LAST use here -> dead before the logit chain.
#pragma unroll
    for (int t = 0; t < 4; t++) {
        half8_t av = __builtin_bit_cast(half8_t, afr[t]);
        int eb = t * 16 + bq * 4;
#pragma unroll
        for (int u = 0; u < 4; u++) {
            float4_t dd = __builtin_amdgcn_mfma_f32_16x16x32_f16(
                av, __builtin_bit_cast(half8_t, bfr[u]), (float4_t)(0.f), 0, 0, 0);
            int col = u * 16 + bl;
            gtile[(eb + 0) * 66 + col] = (_Float16)dd[0];
            gtile[(eb + 1) * 66 + col] = (_Float16)dd[1];
            gtile[(eb + 2) * 66 + col] = (_Float16)dd[2];
            gtile[(eb + 3) * 66 + col] = (_Float16)dd[3];
        }
    }
    const uint* grow = (const uint*)(wbase + (size_t)lane * 132);

    const uint2* p1h = (const uint2*)(P1h + (size_t)dst * 64);
    const uint2* p2h = (const uint2*)(P2h + (size_t)src * 64);
    float logit = ba2[0];
#pragma unroll
    for (int q = 0; q < 16; q++) {
        uint2 ua = p1h[q];
        uint2 ub = p2h[q];
        half2_t s01 = __builtin_bit_cast(half2_t, ua.x) + __builtin_bit_cast(half2_t, ub.x)
                    + __builtin_bit_cast(half2_t, grow[2 * q + 0]);
        half2_t s23 = __builtin_bit_cast(half2_t, ua.y) + __builtin_bit_cast(half2_t, ub.y)
                    + __builtin_bit_cast(half2_t, grow[2 * q + 1]);
        logit = fmaf(silu_f((float)s01.x), Wa2[4 * q + 0], logit);
        logit = fmaf(silu_f((float)s01.y), Wa2[4 * q + 1], logit);
        logit = fmaf(silu_f((float)s23.x), Wa2[4 * q + 2], logit);
        logit = fmaf(silu_f((float)s23.y), Wa2[4 * q + 3], logit);
    }
    float att = __fdividef(1.f, 1.f + __expf(-logit));

    attsh[i] = make_float4(att, sh0, sh1, sh2);
    srcbuf[i] = src;
}

// ================= gather: NPW nodes per wave (round-11 proven) =========
static constexpr int NPW = 5;
__global__ __launch_bounds__(256, 4) void k_gather_mfma(
    const float* __restrict__ scalars, const float* __restrict__ vectors,
    const _Float16* __restrict__ sc16p, const _Float16* __restrict__ vec16p,
    const float* __restrict__ b2,
    const int* __restrict__ row_start,
    const float4* __restrict__ attsh, const int* __restrict__ srcbuf,
    const uint* __restrict__ hbuf, const uint* __restrict__ tbl2,
    float* __restrict__ out)
{
    int wid  = threadIdx.x >> 6;
    int lane = threadIdx.x & 63;
    int gw   = blockIdx.x * 4 + wid;      // 2000*4 = 8000 waves
    int bl = lane & 15, bq = lane >> 4;

    uint4 bfr2[6];
#pragma unroll
    for (int u = 0; u < 6; u++)
        bfr2[u] = *(const uint4*)(tbl2 + (u * 16 + bl) * 16 + bq * 4);

    float b2s[4];
#pragma unroll
    for (int u = 0; u < 4; u++) b2s[u] = b2[u * 16 + bl];
    float bvf = b2[64 + bl], bvg = b2[80 + bl];

    int n0 = gw * NPW;
    for (int nn = 0; nn < NPW; nn++) {
        int n = n0 + nn;
        int rs = rfl(row_start[n]);
        int re = rfl(row_start[n + 1]);

        float accS0 = 0.f, accS1 = 0.f, accS2 = 0.f, accS3 = 0.f;
        float accV0 = 0.f, accV1 = 0.f, accV2 = 0.f;

        for (int i0 = rs; i0 < re; i0 += 16) {
            uint4 av4 = make_uint4(0u, 0u, 0u, 0u);
            if (i0 + bl < re)
                av4 = *(const uint4*)(hbuf + (size_t)(i0 + bl) * 16 + bq * 4);
            half8_t av = __builtin_bit_cast(half8_t, av4);

            float4_t d0 = __builtin_amdgcn_mfma_f32_16x16x32_f16(av, __builtin_bit_cast(half8_t, bfr2[0]), (float4_t)(0.f), 0, 0, 0);
            float4_t d1 = __builtin_amdgcn_mfma_f32_16x16x32_f16(av, __builtin_bit_cast(half8_t, bfr2[1]), (float4_t)(0.f), 0, 0, 0);
            float4_t d2 = __builtin_amdgcn_mfma_f32_16x16x32_f16(av, __builtin_bit_cast(half8_t, bfr2[2]), (float4_t)(0.f), 0, 0, 0);
            float4_t d3 = __builtin_amdgcn_mfma_f32_16x16x32_f16(av, __builtin_bit_cast(half8_t, bfr2[3]), (float4_t)(0.f), 0, 0, 0);
            float4_t d4 = __builtin_amdgcn_mfma_f32_16x16x32_f16(av, __builtin_bit_cast(half8_t, bfr2[4]), (float4_t)(0.f), 0, 0, 0);
            float4_t d5 = __builtin_amdgcn_mfma_f32_16x16x32_f16(av, __builtin_bit_cast(half8_t, bfr2[5]), (float4_t)(0.f), 0, 0, 0);

#pragma unroll
            for (int r = 0; r < 4; r++) {
                int slot = i0 + bq * 4 + r;
                int ok = (slot < re);
                int cs = ok ? slot : (re - 1);
                float4 as = attsh[cs];
                float att = ok ? as.x : 0.f;
                int src = srcbuf[cs];
                uint2 su = *(const uint2*)(sc16p + (size_t)src * 64 + bl * 4);
                uint2 vu = *(const uint2*)(vec16p + (size_t)src * 64 + bl * 4);
                half2_t s01 = __builtin_bit_cast(half2_t, su.x);
                half2_t s23 = __builtin_bit_cast(half2_t, su.y);
                half2_t v01 = __builtin_bit_cast(half2_t, vu.x);
                half2_t v23 = __builtin_bit_cast(half2_t, vu.y);
                accS0 = fmaf(att * (float)s01.x, d0[r] + b2s[0], accS0);
                accS1 = fmaf(att * (float)s01.y, d1[r] + b2s[1], accS1);
                accS2 = fmaf(att * (float)s23.x, d2[r] + b2s[2], accS2);
                accS3 = fmaf(att * (float)s23.y, d3[r] + b2s[3], accS3);
                float vf = d4[r] + bvf;
                float vg = d5[r] + bvg;
                accV0 = fmaf(att, fmaf((float)v01.x, vf, vg * as.y), accV0);
                accV1 = fmaf(att, fmaf((float)v01.y, vf, vg * as.z), accV1);
                accV2 = fmaf(att, fmaf((float)v23.x, vf, vg * as.w), accV2);
            }
        }

        accS0 += __shfl_xor(accS0, 16, 64); accS0 += __shfl_xor(accS0, 32, 64);
        accS1 += __shfl_xor(accS1, 16, 64); accS1 += __shfl_xor(accS1, 32, 64);
        accS2 += __shfl_xor(accS2, 16, 64); accS2 += __shfl_xor(accS2, 32, 64);
        accS3 += __shfl_xor(accS3, 16, 64); accS3 += __shfl_xor(accS3, 32, 64);
        accV0 += __shfl_xor(accV0, 16, 64); accV0 += __shfl_xor(accV0, 32, 64);
        accV1 += __shfl_xor(accV1, 16, 64); accV1 += __shfl_xor(accV1, 32, 64);
        accV2 += __shfl_xor(accV2, 16, 64); accV2 += __shfl_xor(accV2, 32, 64);

        if (bq == 0) {
            size_t o = (size_t)n * 64 + bl;
            out[o +  0] = scalars[o +  0] + accS0;
            out[o + 16] = scalars[o + 16] + accS1;
            out[o + 32] = scalars[o + 32] + accS2;
            out[o + 48] = scalars[o + 48] + accS3;
            size_t ov = (size_t)n * 48 + 3 * bl;
            out[NS + ov + 0] = vectors[ov + 0] + accV0;
            out[NS + ov + 1] = vectors[ov + 1] + accV1;
            out[NS + ov + 2] = vectors[ov + 2] + accV2;
        }
    }
}

extern "C" void kernel_launch(void* const* d_in, const int* in_sizes, int n_in,
                              void* d_out, int out_size, void* d_ws, size_t ws_size,
                              hipStream_t stream)
{
    const float* scalars  = (const float*)d_in[0];
    const float* vectors  = (const float*)d_in[1];
    const float* edge_vec = (const float*)d_in[2];
    const float* W1  = (const float*)d_in[3];
    const float* b1  = (const float*)d_in[4];
    const float* W2  = (const float*)d_in[5];
    const float* b2  = (const float*)d_in[6];
    const float* Wa1 = (const float*)d_in[7];
    const float* ba1 = (const float*)d_in[8];
    const float* Wa2 = (const float*)d_in[9];
    const float* ba2 = (const float*)d_in[10];
    const int* eidx  = (const int*)d_in[11];

    char* wsb = (char*)d_ws;
    // round-12 proven layout + cnt8 (20.48MB) + pre8 (1.28MB) after rec:
    // region used: hbuf 81.92 + tbls 0.01 + P1h/P2h/sc16p 15.36 + rec 20.48
    // + cnt8 20.48 + pre8 1.28 = 139.6MB < 163.84MB reserved. vec16p in dead P1.
    float4* attsh = (float4*)wsb;                       // E float4
    float*  P1    = (float*)(wsb + (size_t)E_ * 16);    // NS floats (dead -> vec16p)
    float*  P2    = P1 + NS;                            // NS floats (dead)
    float*  hbuf  = P2 + NS;                            // region start: 32E floats
    int* cnt       = (int*)(hbuf + (size_t)32 * E_);    // N (unused legacy)
    int* bsum      = cnt + N_;                          // 40
    int* row_start = cnt + 2 * N_;                      // N+1
    int* perm      = row_start + N_ + 1;                // E (dead)
    int* srcbuf    = perm + E_;                         // E (written by k_edges)
    int*  rnk  = (int*)hbuf;                            // aliases hbuf head (dead after k_place3)
    uint* tbl  = (uint*)hbuf + (size_t)16 * E_;         // 1536
    uint* tbl2 = tbl + 1536;                            // 1536
    _Float16* P1h  = (_Float16*)(tbl2 + 1536);          // NS halves
    _Float16* P2h  = P1h + NS;                          // NS halves
    _Float16* sc16p = P2h + NS;                         // NS halves (permuted order)
    _Float16* vec16p = (_Float16*)P1;                   // N*64 halves (permuted+padded)
    float4* rec = (float4*)(sc16p + NS);                // E float4 (packed edge records)
    int* cnt8   = (int*)(rec + E_);                     // N*8*16 ints (XCC-local padded copies)
    int* pre8   = cnt8 + (size_t)N_ * 8 * 16;           // N*8 ints (per-copy prefixes)

    hipMemsetAsync(cnt8, 0, (size_t)N_ * 8 * 16 * sizeof(int), stream);
    k_front1<<<6262, 256, 0, stream>>>(eidx, cnt8, rnk, scalars, vectors,
                                       sc16p, vec16p, W1, Wa1, W2, tbl, tbl2);
    k_scan1<<<40, 1024, 0, stream>>>(cnt8, pre8, row_start, bsum);
    k_scan3<<<40, 1024, 0, stream>>>(bsum, row_start);
    k_place3<<<5000, 256, 0, stream>>>(eidx, edge_vec, row_start, pre8, rnk, rec);
    k_patt<<<PATT_BLOCKS, 256, 0, stream>>>(scalars, Wa1, ba1, P1h, P2h);
    k_edges_sorted<<<5000, 256, 0, stream>>>(rec, P1h, P2h,
                                             tbl, b1, Wa2, ba2,
                                             attsh, srcbuf, (uint*)hbuf);
    k_gather_mfma<<<2000, 256, 0, stream>>>(scalars, vectors, sc16p, vec16p, b2, row_start,
                                            attsh, srcbuf, (const uint*)hbuf, tbl2,
                                            (float*)d_out);
}

// Round 17
// 353.403 us; speedup vs baseline: 1.0996x; 1.0996x over previous
//
#include <hip/hip_runtime.h>

static constexpr int N_ = 40000;
static constexpr int E_ = 1280000;
static constexpr int NS = N_ * 64;      // 2,560,000 scalar elems
static constexpr int NV = N_ * 48;      // 1,920,000 vector elems
static constexpr int HB = 40;           // histogram blocks
static constexpr int CHUNK = E_ / HB;   // 32000 edges per block

typedef _Float16 half2_t __attribute__((ext_vector_type(2)));
typedef _Float16 half8_t __attribute__((ext_vector_type(8)));
typedef float float4_t __attribute__((ext_vector_type(4)));
typedef unsigned int uint;

__device__ __forceinline__ float silu_f(float x) { return __fdividef(x, 1.f + __expf(-x)); }
__device__ __forceinline__ int rfl(int x) { return __builtin_amdgcn_readfirstlane(x); }

// ============ rank WITHOUT global atomics: block-local LDS histogram ==========
// r12/r15/r16 showed ~75-85us stuck in the 1.28M global atomicAdds regardless
// of padding (r15 null) or XCC-replication (r16 WORSE: 20MB working set fell
// out of L2 -> HBM RMW). Fix: counting sort. Each block owns a contiguous
// 32000-edge chunk and histograms dst into a FULL 40000-bin LDS array
// (156.25KB static, <=160KB/CU; 8-phase GEMM template already uses 128KB).
// LDS atomics are bank-parallel: zero fabric traffic. rloc = rank within
// (block,dst); cntB[b][dst] = per-block counts.
__global__ __launch_bounds__(1024) void k_hist(
    const int* __restrict__ eidx, int* __restrict__ cntB, int* __restrict__ rloc)
{
    __shared__ int bins[N_];               // 156.25 KB
    int b = blockIdx.x, tid = threadIdx.x;
    for (int j = tid; j < N_; j += 1024) bins[j] = 0;
    __syncthreads();
    int e0 = b * CHUNK;
    for (int e = e0 + tid; e < e0 + CHUNK; e += 1024)
        rloc[e] = atomicAdd(&bins[eidx[E_ + e]], 1);
    __syncthreads();
    for (int j = tid; j < N_; j += 1024) cntB[b * N_ + j] = bins[j];   // coalesced dump
}

// ====== scanB: in-place exclusive prefix over blocks per dst + node totals ====
// For fixed c, threads read cntB[c*N_+idx] with consecutive idx -> coalesced.
__global__ void k_scanB(int* __restrict__ cntB, int* __restrict__ row_start,
                        int* __restrict__ bsum)
{
    __shared__ int buf[1024];
    int b = blockIdx.x, tid = threadIdx.x;
    int idx = b * 1024 + tid;
    int v = 0;
    if (idx < N_) {
        for (int c = 0; c < HB; c++) {
            int t = cntB[c * N_ + idx];
            cntB[c * N_ + idx] = v;        // exclusive prefix over blocks
            v += t;
        }
    }
    buf[tid] = v;
    __syncthreads();
    for (int off = 1; off < 1024; off <<= 1) {
        int t = (tid >= off) ? buf[tid - off] : 0;
        __syncthreads();
        buf[tid] += t;
        __syncthreads();
    }
    if (idx < N_) row_start[idx] = buf[tid] - v;
    if (tid == 1023) bsum[b] = buf[1023];
}

// fused scan2+scan3: each block serially sums bsum[0..b-1] (<=40 ints)
__global__ void k_scan3(const int* __restrict__ bsum, int* __restrict__ row_start)
{
    __shared__ int boffs;
    if (threadIdx.x == 0) {
        int s = 0;
        for (int b = 0; b < (int)blockIdx.x; b++) s += bsum[b];
        boffs = s;
    }
    __syncthreads();
    int idx = blockIdx.x * 1024 + threadIdx.x;
    if (idx < N_) row_start[idx] += boffs;
    if (idx == N_) row_start[N_] = E_;
}

// place ONE 16B record per edge into sorted slot (round-12 proven store shape):
// slot = row_start[dst] + cntB[e/CHUNK][dst] + rloc[e].
__global__ void k_place3b(const int* __restrict__ eidx, const float* __restrict__ edge_vec,
                          const int* __restrict__ row_start, const int* __restrict__ cntB,
                          const int* __restrict__ rloc, float4* __restrict__ rec)
{
    int e = blockIdx.x * 256 + threadIdx.x;
    int src = eidx[e];
    int dst = eidx[E_ + e];
    int b = e / CHUNK;
    size_t slot = (size_t)(row_start[dst] + cntB[b * N_ + dst] + rloc[e]);
    uint sd = (uint)src | ((uint)dst << 16);
    rec[slot] = make_float4(edge_vec[3 * e + 0], edge_vec[3 * e + 1],
                            edge_vec[3 * e + 2], __uint_as_float(sd));
}

// ---- per-node attention precompute, wave-resident weights (round-2 proven) ----
static constexpr int PATT_BLOCKS = 512;              // 2048 waves
__global__ __launch_bounds__(256) void k_patt(
    const float* __restrict__ scalars, const float* __restrict__ Wa1,
    const float* __restrict__ ba1,
    _Float16* __restrict__ P1h, _Float16* __restrict__ P2h)
{
    int gw   = (blockIdx.x * 256 + threadIdx.x) >> 6;  // global wave id
    int lane = threadIdx.x & 63;
    float w[128];
#pragma unroll
    for (int k = 0; k < 128; k++) w[k] = Wa1[k * 64 + lane];
    float bias = ba1[lane];
    for (int n = gw; n < N_; n += PATT_BLOCKS * 4) {
        float sv = scalars[(size_t)n * 64 + lane];
        float a1 = bias, a2 = 0.f;
#pragma unroll
        for (int k = 0; k < 64; k++) {
            float sk = __shfl(sv, k, 64);
            a1 = fmaf(sk, w[k], a1);
            a2 = fmaf(sk, w[64 + k], a2);
        }
        P1h[(size_t)n * 64 + lane] = (_Float16)a1;
        P2h[(size_t)n * 64 + lane] = (_Float16)a2;
    }
}

// ---- f16 tables in MFMA order + fused weight-table pack (round-7 proven) ----
__global__ void k_convp(const float* __restrict__ scalars, const float* __restrict__ vectors,
                        _Float16* __restrict__ sc16p, _Float16* __restrict__ vec16p,
                        const float* __restrict__ W1, const float* __restrict__ Wa1,
                        const float* __restrict__ W2, uint* __restrict__ tbl,
                        uint* __restrict__ tbl2)
{
    if (blockIdx.x >= 5000) {                          // fused k_pack (12 tail blocks)
        int t = (blockIdx.x - 5000) * 256 + threadIdx.x;
        if (t < 1536) {
            int j = t >> 4, q = t & 15;
            int k0 = 2 * q, k1 = 2 * q + 1;
            float a = (j < 64) ? Wa1[(128 + k0) * 64 + j] : W1[k0 * 32 + (j - 64)];
            float b = (j < 64) ? Wa1[(128 + k1) * 64 + j] : W1[k1 * 32 + (j - 64)];
            half2_t v; v.x = (_Float16)a; v.y = (_Float16)b;
            tbl[t] = __builtin_bit_cast(uint, v);
        } else if (t < 3072) {
            int tt = t - 1536;
            int j = tt >> 4, q = tt & 15;
            half2_t v;
            v.x = (_Float16)W2[(2 * q + 0) * 96 + j];
            v.y = (_Float16)W2[(2 * q + 1) * 96 + j];
            tbl2[tt] = __builtin_bit_cast(uint, v);
        }
        return;
    }
    int t = blockIdx.x * 256 + threadIdx.x;            // 5000*256 = N_*32 exactly
    if (t < N_ * 16) {
        int n = t >> 4, bl = t & 15;
        const float* srow = scalars + (size_t)n * 64;
        half2_t a, b;
        a.x = (_Float16)srow[bl];
        a.y = (_Float16)srow[16 + bl];
        b.x = (_Float16)srow[32 + bl];
        b.y = (_Float16)srow[48 + bl];
        uint2 u; u.x = __builtin_bit_cast(uint, a); u.y = __builtin_bit_cast(uint, b);
        *(uint2*)(sc16p + (size_t)n * 64 + bl * 4) = u;
    } else {
        int tt = t - N_ * 16;
        int n = tt >> 4, bl = tt & 15;
        const float* vrow = vectors + (size_t)n * 48 + bl * 3;
        half2_t a, b;
        a.x = (_Float16)vrow[0];
        a.y = (_Float16)vrow[1];
        b.x = (_Float16)vrow[2];
        b.y = (_Float16)0.f;
        uint2 u; u.x = __builtin_bit_cast(uint, a); u.y = __builtin_bit_cast(uint, b);
        *(uint2*)(vec16p + (size_t)n * 64 + bl * 4) = u;
    }
}

// ================= edge phase: round-12 proven (split-phase, H-first, 52 VGPR) =
__global__ __launch_bounds__(256, 3) void k_edges_sorted(
    const float4* __restrict__ rec,
    const _Float16* __restrict__ P1h, const _Float16* __restrict__ P2h,
    const uint* __restrict__ tbl, const float* __restrict__ b1,
    const float* __restrict__ Wa2, const float* __restrict__ ba2,
    float4* __restrict__ attsh, int* __restrict__ srcbuf, uint* __restrict__ hbufp)
{
    __shared__ char lds_raw[4 * 8448];
    int tid = threadIdx.x;
    int wid = tid >> 6, lane = tid & 63;
    char* wbase = lds_raw + wid * 8448;
    int bl = lane & 15, bq = lane >> 4;

    int i = blockIdx.x * 256 + tid;        // i IS the sorted slot
    float4 ra = rec[(size_t)i];
    float ev0 = ra.x, ev1 = ra.y, ev2 = ra.z;
    uint sd = __float_as_uint(ra.w);
    int src = (int)(sd & 0xffffu);
    int dst = (int)(sd >> 16);

    float d = sqrtf(fmaf(ev0, ev0, fmaf(ev1, ev1, ev2 * ev2)));
    float inv_d = __fdividef(1.f, fmaxf(d, 1e-8f));
    float cut = (d < 10.f) ? 0.5f * (__cosf(0.31415927f * d) + 1.f) : 0.f;
    float cutd = cut * inv_d;
    float sh0 = ev1 * inv_d, sh1 = ev2 * inv_d, sh2 = ev0 * inv_d;

    // rbf via sin recurrence: sin((k+1)t) = 2cos(t)sin(kt) - sin((k-1)t)
    float th = 0.31415927f * d;
    float scur = __sinf(th);
    float twoC = 2.f * __cosf(th);
    float sprev = 0.f;
    uint rbf2[16];
#pragma unroll
    for (int q = 0; q < 16; q++) {
        float r0 = scur * cutd;
        float snext = fmaf(twoC, scur, -sprev);
        sprev = scur; scur = snext;
        float r1 = scur * cutd;
        snext = fmaf(twoC, scur, -sprev);
        sprev = scur; scur = snext;
        half2_t v; v.x = (_Float16)r0; v.y = (_Float16)r1;
        rbf2[q] = __builtin_bit_cast(uint, v);
    }
    {
        uint4* rw = (uint4*)(wbase + lane * 64);
        rw[0] = make_uint4(rbf2[0], rbf2[1], rbf2[2], rbf2[3]);
        rw[1] = make_uint4(rbf2[4], rbf2[5], rbf2[6], rbf2[7]);
        rw[2] = make_uint4(rbf2[8], rbf2[9], rbf2[10], rbf2[11]);
        rw[3] = make_uint4(rbf2[12], rbf2[13], rbf2[14], rbf2[15]);
    }
    uint4 bfr[6];
#pragma unroll
    for (int u = 0; u < 6; u++)
        bfr[u] = *(const uint4*)(tbl + (u * 16 + bl) * 16 + bq * 4);

    uint4 afr[4];
#pragma unroll
    for (int t = 0; t < 4; t++)
        afr[t] = *(const uint4*)(wbase + (t * 16 + bl) * 64 + bq * 16);

    _Float16* gtile = (_Float16*)wbase;

    // ---- phase H (FIRST): h filter cols 0..31 into stride-34 tile ----
#pragma unroll
    for (int t = 0; t < 4; t++) {
        half8_t av = __builtin_bit_cast(half8_t, afr[t]);
        int eb = t * 16 + bq * 4;
#pragma unroll
        for (int u = 4; u < 6; u++) {
            float4_t dd = __builtin_amdgcn_mfma_f32_16x16x32_f16(
                av, __builtin_bit_cast(half8_t, bfr[u]), (float4_t)(0.f), 0, 0, 0);
            int col = (u - 4) * 16 + bl;
            gtile[(eb + 0) * 34 + col] = (_Float16)dd[0];
            gtile[(eb + 1) * 34 + col] = (_Float16)dd[1];
            gtile[(eb + 2) * 34 + col] = (_Float16)dd[2];
            gtile[(eb + 3) * 34 + col] = (_Float16)dd[3];
        }
    }
    {
        const uint* growB = (const uint*)(wbase + (size_t)lane * 68);
        uint hp[16];
#pragma unroll
        for (int q = 0; q < 16; q++) {
            half2_t gg = __builtin_bit_cast(half2_t, growB[q]);
            half2_t v;
            v.x = (_Float16)silu_f((float)gg.x + b1[2 * q + 0]);
            v.y = (_Float16)silu_f((float)gg.y + b1[2 * q + 1]);
            hp[q] = __builtin_bit_cast(uint, v);
        }
        uint4* hrow4 = (uint4*)(hbufp + (size_t)i * 16);
#pragma unroll
        for (int q = 0; q < 4; q++)
            hrow4[q] = make_uint4(hp[4 * q + 0], hp[4 * q + 1], hp[4 * q + 2], hp[4 * q + 3]);
    }

    // ---- phase A: att filter cols 0..63 into stride-66 tile (same buffer) ----
    // afr/bfr have their LAST use here -> dead before the logit chain.
#pragma unroll
    for (int t = 0; t < 4; t++) {
        half8_t av = __builtin_bit_cast(half8_t, afr[t]);
        int eb = t * 16 + bq * 4;
#pragma unroll
        for (int u = 0; u < 4; u++) {
            float4_t dd = __builtin_amdgcn_mfma_f32_16x16x32_f16(
                av, __builtin_bit_cast(half8_t, bfr[u]), (float4_t)(0.f), 0, 0, 0);
            int col = u * 16 + bl;
            gtile[(eb + 0) * 66 + col] = (_Float16)dd[0];
            gtile[(eb + 1) * 66 + col] = (_Float16)dd[1];
            gtile[(eb + 2) * 66 + col] = (_Float16)dd[2];
            gtile[(eb + 3) * 66 + col] = (_Float16)dd[3];
        }
    }
    const uint* grow = (const uint*)(wbase + (size_t)lane * 132);

    const uint2* p1h = (const uint2*)(P1h + (size_t)dst * 64);
    const uint2* p2h = (const uint2*)(P2h + (size_t)src * 64);
    float logit = ba2[0];
#pragma unroll
    for (int q = 0; q < 16; q++) {
        uint2 ua = p1h[q];
        uint2 ub = p2h[q];
        half2_t s01 = __builtin_bit_cast(half2_t, ua.x) + __builtin_bit_cast(half2_t, ub.x)
                    + __builtin_bit_cast(half2_t, grow[2 * q + 0]);
        half2_t s23 = __builtin_bit_cast(half2_t, ua.y) + __builtin_bit_cast(half2_t, ub.y)
                    + __builtin_bit_cast(half2_t, grow[2 * q + 1]);
        logit = fmaf(silu_f((float)s01.x), Wa2[4 * q + 0], logit);
        logit = fmaf(silu_f((float)s01.y), Wa2[4 * q + 1], logit);
        logit = fmaf(silu_f((float)s23.x), Wa2[4 * q + 2], logit);
        logit = fmaf(silu_f((float)s23.y), Wa2[4 * q + 3], logit);
    }
    float att = __fdividef(1.f, 1.f + __expf(-logit));

    attsh[i] = make_float4(att, sh0, sh1, sh2);
    srcbuf[i] = src;
}

// ================= gather: NPW nodes per wave (round-11 proven) =========
static constexpr int NPW = 5;
__global__ __launch_bounds__(256, 4) void k_gather_mfma(
    const float* __restrict__ scalars, const float* __restrict__ vectors,
    const _Float16* __restrict__ sc16p, const _Float16* __restrict__ vec16p,
    const float* __restrict__ b2,
    const int* __restrict__ row_start,
    const float4* __restrict__ attsh, const int* __restrict__ srcbuf,
    const uint* __restrict__ hbuf, const uint* __restrict__ tbl2,
    float* __restrict__ out)
{
    int wid  = threadIdx.x >> 6;
    int lane = threadIdx.x & 63;
    int gw   = blockIdx.x * 4 + wid;      // 2000*4 = 8000 waves
    int bl = lane & 15, bq = lane >> 4;

    uint4 bfr2[6];
#pragma unroll
    for (int u = 0; u < 6; u++)
        bfr2[u] = *(const uint4*)(tbl2 + (u * 16 + bl) * 16 + bq * 4);

    float b2s[4];
#pragma unroll
    for (int u = 0; u < 4; u++) b2s[u] = b2[u * 16 + bl];
    float bvf = b2[64 + bl], bvg = b2[80 + bl];

    int n0 = gw * NPW;
    for (int nn = 0; nn < NPW; nn++) {
        int n = n0 + nn;
        int rs = rfl(row_start[n]);
        int re = rfl(row_start[n + 1]);

        float accS0 = 0.f, accS1 = 0.f, accS2 = 0.f, accS3 = 0.f;
        float accV0 = 0.f, accV1 = 0.f, accV2 = 0.f;

        for (int i0 = rs; i0 < re; i0 += 16) {
            uint4 av4 = make_uint4(0u, 0u, 0u, 0u);
            if (i0 + bl < re)
                av4 = *(const uint4*)(hbuf + (size_t)(i0 + bl) * 16 + bq * 4);
            half8_t av = __builtin_bit_cast(half8_t, av4);

            float4_t d0 = __builtin_amdgcn_mfma_f32_16x16x32_f16(av, __builtin_bit_cast(half8_t, bfr2[0]), (float4_t)(0.f), 0, 0, 0);
            float4_t d1 = __builtin_amdgcn_mfma_f32_16x16x32_f16(av, __builtin_bit_cast(half8_t, bfr2[1]), (float4_t)(0.f), 0, 0, 0);
            float4_t d2 = __builtin_amdgcn_mfma_f32_16x16x32_f16(av, __builtin_bit_cast(half8_t, bfr2[2]), (float4_t)(0.f), 0, 0, 0);
            float4_t d3 = __builtin_amdgcn_mfma_f32_16x16x32_f16(av, __builtin_bit_cast(half8_t, bfr2[3]), (float4_t)(0.f), 0, 0, 0);
            float4_t d4 = __builtin_amdgcn_mfma_f32_16x16x32_f16(av, __builtin_bit_cast(half8_t, bfr2[4]), (float4_t)(0.f), 0, 0, 0);
            float4_t d5 = __builtin_amdgcn_mfma_f32_16x16x32_f16(av, __builtin_bit_cast(half8_t, bfr2[5]), (float4_t)(0.f), 0, 0, 0);

#pragma unroll
            for (int r = 0; r < 4; r++) {
                int slot = i0 + bq * 4 + r;
                int ok = (slot < re);
                int cs = ok ? slot : (re - 1);
                float4 as = attsh[cs];
                float att = ok ? as.x : 0.f;
                int src = srcbuf[cs];
                uint2 su = *(const uint2*)(sc16p + (size_t)src * 64 + bl * 4);
                uint2 vu = *(const uint2*)(vec16p + (size_t)src * 64 + bl * 4);
                half2_t s01 = __builtin_bit_cast(half2_t, su.x);
                half2_t s23 = __builtin_bit_cast(half2_t, su.y);
                half2_t v01 = __builtin_bit_cast(half2_t, vu.x);
                half2_t v23 = __builtin_bit_cast(half2_t, vu.y);
                accS0 = fmaf(att * (float)s01.x, d0[r] + b2s[0], accS0);
                accS1 = fmaf(att * (float)s01.y, d1[r] + b2s[1], accS1);
                accS2 = fmaf(att * (float)s23.x, d2[r] + b2s[2], accS2);
                accS3 = fmaf(att * (float)s23.y, d3[r] + b2s[3], accS3);
                float vf = d4[r] + bvf;
                float vg = d5[r] + bvg;
                accV0 = fmaf(att, fmaf((float)v01.x, vf, vg * as.y), accV0);
                accV1 = fmaf(att, fmaf((float)v01.y, vf, vg * as.z), accV1);
                accV2 = fmaf(att, fmaf((float)v23.x, vf, vg * as.w), accV2);
            }
        }

        accS0 += __shfl_xor(accS0, 16, 64); accS0 += __shfl_xor(accS0, 32, 64);
        accS1 += __shfl_xor(accS1, 16, 64); accS1 += __shfl_xor(accS1, 32, 64);
        accS2 += __shfl_xor(accS2, 16, 64); accS2 += __shfl_xor(accS2, 32, 64);
        accS3 += __shfl_xor(accS3, 16, 64); accS3 += __shfl_xor(accS3, 32, 64);
        accV0 += __shfl_xor(accV0, 16, 64); accV0 += __shfl_xor(accV0, 32, 64);
        accV1 += __shfl_xor(accV1, 16, 64); accV1 += __shfl_xor(accV1, 32, 64);
        accV2 += __shfl_xor(accV2, 16, 64); accV2 += __shfl_xor(accV2, 32, 64);

        if (bq == 0) {
            size_t o = (size_t)n * 64 + bl;
            out[o +  0] = scalars[o +  0] + accS0;
            out[o + 16] = scalars[o + 16] + accS1;
            out[o + 32] = scalars[o + 32] + accS2;
            out[o + 48] = scalars[o + 48] + accS3;
            size_t ov = (size_t)n * 48 + 3 * bl;
            out[NS + ov + 0] = vectors[ov + 0] + accV0;
            out[NS + ov + 1] = vectors[ov + 1] + accV1;
            out[NS + ov + 2] = vectors[ov + 2] + accV2;
        }
    }
}

extern "C" void kernel_launch(void* const* d_in, const int* in_sizes, int n_in,
                              void* d_out, int out_size, void* d_ws, size_t ws_size,
                              hipStream_t stream)
{
    const float* scalars  = (const float*)d_in[0];
    const float* vectors  = (const float*)d_in[1];
    const float* edge_vec = (const float*)d_in[2];
    const float* W1  = (const float*)d_in[3];
    const float* b1  = (const float*)d_in[4];
    const float* W2  = (const float*)d_in[5];
    const float* b2  = (const float*)d_in[6];
    const float* Wa1 = (const float*)d_in[7];
    const float* ba1 = (const float*)d_in[8];
    const float* Wa2 = (const float*)d_in[9];
    const float* ba2 = (const float*)d_in[10];
    const int* eidx  = (const int*)d_in[11];

    char* wsb = (char*)d_ws;
    // round-12 proven layout + cntB (6.4MB) after rec:
    // region used: hbuf 81.92 + tbls 0.01 + P1h/P2h/sc16p 15.36 + rec 20.48
    // + cntB 6.4 = 124.2MB < 163.84MB reserved. vec16p (5.12MB) in dead P1.
    float4* attsh = (float4*)wsb;                       // E float4
    float*  P1    = (float*)(wsb + (size_t)E_ * 16);    // NS floats (dead -> vec16p)
    float*  P2    = P1 + NS;                            // NS floats (dead)
    float*  hbuf  = P2 + NS;                            // region start: 32E floats
    int* cnt       = (int*)(hbuf + (size_t)32 * E_);    // N (unused legacy)
    int* bsum      = cnt + N_;                          // 40
    int* row_start = cnt + 2 * N_;                      // N+1
    int* perm      = row_start + N_ + 1;                // E (dead)
    int* srcbuf    = perm + E_;                         // E (written by k_edges)
    int*  rloc = (int*)hbuf;                            // aliases hbuf head (dead after k_place3b)
    uint* tbl  = (uint*)hbuf + (size_t)16 * E_;         // 1536
    uint* tbl2 = tbl + 1536;                            // 1536
    _Float16* P1h  = (_Float16*)(tbl2 + 1536);          // NS halves
    _Float16* P2h  = P1h + NS;                          // NS halves
    _Float16* sc16p = P2h + NS;                         // NS halves (permuted order)
    _Float16* vec16p = (_Float16*)P1;                   // N*64 halves (permuted+padded)
    float4* rec = (float4*)(sc16p + NS);                // E float4 (packed edge records)
    int* cntB   = (int*)(rec + E_);                     // HB*N_ ints (per-block counts)

    k_hist<<<HB, 1024, 0, stream>>>(eidx, cntB, rloc);
    k_scanB<<<40, 1024, 0, stream>>>(cntB, row_start, bsum);
    k_scan3<<<40, 1024, 0, stream>>>(bsum, row_start);
    k_place3b<<<5000, 256, 0, stream>>>(eidx, edge_vec, row_start, cntB, rloc, rec);
    k_patt<<<PATT_BLOCKS, 256, 0, stream>>>(scalars, Wa1, ba1, P1h, P2h);
    k_convp<<<5012, 256, 0, stream>>>(scalars, vectors, sc16p, vec16p, W1, Wa1, W2, tbl, tbl2);
    k_edges_sorted<<<5000, 256, 0, stream>>>(rec, P1h, P2h,
                                             tbl, b1, Wa2, ba2,
                                             attsh, srcbuf, (uint*)hbuf);
    k_gather_mfma<<<2000, 256, 0, stream>>>(scalars, vectors, sc16p, vec16p, b2, row_start,
                                            attsh, srcbuf, (const uint*)hbuf, tbl2,
                                            (float*)d_out);
}

// Round 18
// 347.011 us; speedup vs baseline: 1.1198x; 1.0184x over previous
//
#include <hip/hip_runtime.h>

static constexpr int N_ = 40000;
static constexpr int E_ = 1280000;
static constexpr int NS = N_ * 64;      // 2,560,000 scalar elems
static constexpr int NV = N_ * 48;      // 1,920,000 vector elems
static constexpr int HB = 40;           // histogram blocks
static constexpr int CHUNK = E_ / HB;   // 32000 edges per block

typedef _Float16 half2_t __attribute__((ext_vector_type(2)));
typedef _Float16 half8_t __attribute__((ext_vector_type(8)));
typedef float float4_t __attribute__((ext_vector_type(4)));
typedef unsigned int uint;

__device__ __forceinline__ float silu_f(float x) { return __fdividef(x, 1.f + __expf(-x)); }
__device__ __forceinline__ int rfl(int x) { return __builtin_amdgcn_readfirstlane(x); }

// ============ rank WITHOUT global atomics: block-local LDS histogram ==========
// (round-17 proven: replaces memset+global-atomic rank; LDS atomics are
// bank-parallel, zero fabric traffic)
__global__ __launch_bounds__(1024) void k_hist(
    const int* __restrict__ eidx, int* __restrict__ cntB, int* __restrict__ rloc)
{
    __shared__ int bins[N_];               // 156.25 KB
    int b = blockIdx.x, tid = threadIdx.x;
    for (int j = tid; j < N_; j += 1024) bins[j] = 0;
    __syncthreads();
    int e0 = b * CHUNK;
    for (int e = e0 + tid; e < e0 + CHUNK; e += 1024)
        rloc[e] = atomicAdd(&bins[eidx[E_ + e]], 1);
    __syncthreads();
    for (int j = tid; j < N_; j += 1024) cntB[b * N_ + j] = bins[j];   // coalesced dump
}

// ====== scanB: in-place exclusive prefix over blocks per dst + node totals ====
__global__ void k_scanB(int* __restrict__ cntB, int* __restrict__ row_start,
                        int* __restrict__ bsum)
{
    __shared__ int buf[1024];
    int b = blockIdx.x, tid = threadIdx.x;
    int idx = b * 1024 + tid;
    int v = 0;
    if (idx < N_) {
        for (int c = 0; c < HB; c++) {
            int t = cntB[c * N_ + idx];
            cntB[c * N_ + idx] = v;        // exclusive prefix over blocks
            v += t;
        }
    }
    buf[tid] = v;
    __syncthreads();
    for (int off = 1; off < 1024; off <<= 1) {
        int t = (tid >= off) ? buf[tid - off] : 0;
        __syncthreads();
        buf[tid] += t;
        __syncthreads();
    }
    if (idx < N_) row_start[idx] = buf[tid] - v;
    if (tid == 1023) bsum[b] = buf[1023];
}

// fused scan2+scan3: each block serially sums bsum[0..b-1] (<=40 ints)
__global__ void k_scan3(const int* __restrict__ bsum, int* __restrict__ row_start)
{
    __shared__ int boffs;
    if (threadIdx.x == 0) {
        int s = 0;
        for (int b = 0; b < (int)blockIdx.x; b++) s += bsum[b];
        boffs = s;
    }
    __syncthreads();
    int idx = blockIdx.x * 1024 + threadIdx.x;
    if (idx < N_) row_start[idx] += boffs;
    if (idx == N_) row_start[N_] = E_;
}

// place ONE 16B record per edge into sorted slot (round-12 proven store shape):
// slot = row_start[dst] + cntB[e/CHUNK][dst] + rloc[e].
__global__ void k_place3b(const int* __restrict__ eidx, const float* __restrict__ edge_vec,
                          const int* __restrict__ row_start, const int* __restrict__ cntB,
                          const int* __restrict__ rloc, float4* __restrict__ rec)
{
    int e = blockIdx.x * 256 + threadIdx.x;
    int src = eidx[e];
    int dst = eidx[E_ + e];
    int b = e / CHUNK;
    size_t slot = (size_t)(row_start[dst] + cntB[b * N_ + dst] + rloc[e]);
    uint sd = (uint)src | ((uint)dst << 16);
    rec[slot] = make_float4(edge_vec[3 * e + 0], edge_vec[3 * e + 1],
                            edge_vec[3 * e + 2], __uint_as_float(sd));
}

// ---- per-node attention precompute, wave-resident weights (round-2 proven) ----
static constexpr int PATT_BLOCKS = 512;              // 2048 waves
__global__ __launch_bounds__(256) void k_patt(
    const float* __restrict__ scalars, const float* __restrict__ Wa1,
    const float* __restrict__ ba1,
    _Float16* __restrict__ P1h, _Float16* __restrict__ P2h)
{
    int gw   = (blockIdx.x * 256 + threadIdx.x) >> 6;  // global wave id
    int lane = threadIdx.x & 63;
    float w[128];
#pragma unroll
    for (int k = 0; k < 128; k++) w[k] = Wa1[k * 64 + lane];
    float bias = ba1[lane];
    for (int n = gw; n < N_; n += PATT_BLOCKS * 4) {
        float sv = scalars[(size_t)n * 64 + lane];
        float a1 = bias, a2 = 0.f;
#pragma unroll
        for (int k = 0; k < 64; k++) {
            float sk = __shfl(sv, k, 64);
            a1 = fmaf(sk, w[k], a1);
            a2 = fmaf(sk, w[64 + k], a2);
        }
        P1h[(size_t)n * 64 + lane] = (_Float16)a1;
        P2h[(size_t)n * 64 + lane] = (_Float16)a2;
    }
}

// ---- f16 tables in MFMA order + fused weight-table pack (round-7 proven) ----
__global__ void k_convp(const float* __restrict__ scalars, const float* __restrict__ vectors,
                        _Float16* __restrict__ sc16p, _Float16* __restrict__ vec16p,
                        const float* __restrict__ W1, const float* __restrict__ Wa1,
                        const float* __restrict__ W2, uint* __restrict__ tbl,
                        uint* __restrict__ tbl2)
{
    if (blockIdx.x >= 5000) {                          // fused k_pack (12 tail blocks)
        int t = (blockIdx.x - 5000) * 256 + threadIdx.x;
        if (t < 1536) {
            int j = t >> 4, q = t & 15;
            int k0 = 2 * q, k1 = 2 * q + 1;
            float a = (j < 64) ? Wa1[(128 + k0) * 64 + j] : W1[k0 * 32 + (j - 64)];
            float b = (j < 64) ? Wa1[(128 + k1) * 64 + j] : W1[k1 * 32 + (j - 64)];
            half2_t v; v.x = (_Float16)a; v.y = (_Float16)b;
            tbl[t] = __builtin_bit_cast(uint, v);
        } else if (t < 3072) {
            int tt = t - 1536;
            int j = tt >> 4, q = tt & 15;
            half2_t v;
            v.x = (_Float16)W2[(2 * q + 0) * 96 + j];
            v.y = (_Float16)W2[(2 * q + 1) * 96 + j];
            tbl2[tt] = __builtin_bit_cast(uint, v);
        }
        return;
    }
    int t = blockIdx.x * 256 + threadIdx.x;            // 5000*256 = N_*32 exactly
    if (t < N_ * 16) {
        int n = t >> 4, bl = t & 15;
        const float* srow = scalars + (size_t)n * 64;
        half2_t a, b;
        a.x = (_Float16)srow[bl];
        a.y = (_Float16)srow[16 + bl];
        b.x = (_Float16)srow[32 + bl];
        b.y = (_Float16)srow[48 + bl];
        uint2 u; u.x = __builtin_bit_cast(uint, a); u.y = __builtin_bit_cast(uint, b);
        *(uint2*)(sc16p + (size_t)n * 64 + bl * 4) = u;
    } else {
        int tt = t - N_ * 16;
        int n = tt >> 4, bl = tt & 15;
        const float* vrow = vectors + (size_t)n * 48 + bl * 3;
        half2_t a, b;
        a.x = (_Float16)vrow[0];
        a.y = (_Float16)vrow[1];
        b.x = (_Float16)vrow[2];
        b.y = (_Float16)0.f;
        uint2 u; u.x = __builtin_bit_cast(uint, a); u.y = __builtin_bit_cast(uint, b);
        *(uint2*)(vec16p + (size_t)n * 64 + bl * 4) = u;
    }
}

// ================= edge phase: r12 body, occupancy 3->4 blocks/CU =============
// r8's bounds(256,4) failed because THAT shape needed >64 VGPR -> spill.
// This H-first split-phase shape measures 52 VGPR, under the 64-VGPR clamp
// that (256,4) imposes; LDS 33792B allows 4.7 blocks. 16 waves/CU vs 12.
// Spill tripwire: WRITE_SIZE must stay ~105MB.
__global__ __launch_bounds__(256, 4) void k_edges_sorted(
    const float4* __restrict__ rec,
    const _Float16* __restrict__ P1h, const _Float16* __restrict__ P2h,
    const uint* __restrict__ tbl, const float* __restrict__ b1,
    const float* __restrict__ Wa2, const float* __restrict__ ba2,
    float4* __restrict__ attsh, int* __restrict__ srcbuf, uint* __restrict__ hbufp)
{
    __shared__ char lds_raw[4 * 8448];
    int tid = threadIdx.x;
    int wid = tid >> 6, lane = tid & 63;
    char* wbase = lds_raw + wid * 8448;
    int bl = lane & 15, bq = lane >> 4;

    int i = blockIdx.x * 256 + tid;        // i IS the sorted slot
    float4 ra = rec[(size_t)i];
    float ev0 = ra.x, ev1 = ra.y, ev2 = ra.z;
    uint sd = __float_as_uint(ra.w);
    int src = (int)(sd & 0xffffu);
    int dst = (int)(sd >> 16);

    float d = sqrtf(fmaf(ev0, ev0, fmaf(ev1, ev1, ev2 * ev2)));
    float inv_d = __fdividef(1.f, fmaxf(d, 1e-8f));
    float cut = (d < 10.f) ? 0.5f * (__cosf(0.31415927f * d) + 1.f) : 0.f;
    float cutd = cut * inv_d;
    float sh0 = ev1 * inv_d, sh1 = ev2 * inv_d, sh2 = ev0 * inv_d;

    // rbf via sin recurrence: sin((k+1)t) = 2cos(t)sin(kt) - sin((k-1)t)
    float th = 0.31415927f * d;
    float scur = __sinf(th);
    float twoC = 2.f * __cosf(th);
    float sprev = 0.f;
    uint rbf2[16];
#pragma unroll
    for (int q = 0; q < 16; q++) {
        float r0 = scur * cutd;
        float snext = fmaf(twoC, scur, -sprev);
        sprev = scur; scur = snext;
        float r1 = scur * cutd;
        snext = fmaf(twoC, scur, -sprev);
        sprev = scur; scur = snext;
        half2_t v; v.x = (_Float16)r0; v.y = (_Float16)r1;
        rbf2[q] = __builtin_bit_cast(uint, v);
    }
    {
        uint4* rw = (uint4*)(wbase + lane * 64);
        rw[0] = make_uint4(rbf2[0], rbf2[1], rbf2[2], rbf2[3]);
        rw[1] = make_uint4(rbf2[4], rbf2[5], rbf2[6], rbf2[7]);
        rw[2] = make_uint4(rbf2[8], rbf2[9], rbf2[10], rbf2[11]);
        rw[3] = make_uint4(rbf2[12], rbf2[13], rbf2[14], rbf2[15]);
    }
    uint4 bfr[6];
#pragma unroll
    for (int u = 0; u < 6; u++)
        bfr[u] = *(const uint4*)(tbl + (u * 16 + bl) * 16 + bq * 4);

    uint4 afr[4];
#pragma unroll
    for (int t = 0; t < 4; t++)
        afr[t] = *(const uint4*)(wbase + (t * 16 + bl) * 64 + bq * 16);

    _Float16* gtile = (_Float16*)wbase;

    // ---- phase H (FIRST): h filter cols 0..31 into stride-34 tile ----
#pragma unroll
    for (int t = 0; t < 4; t++) {
        half8_t av = __builtin_bit_cast(half8_t, afr[t]);
        int eb = t * 16 + bq * 4;
#pragma unroll
        for (int u = 4; u < 6; u++) {
            float4_t dd = __builtin_amdgcn_mfma_f32_16x16x32_f16(
                av, __builtin_bit_cast(half8_t, bfr[u]), (float4_t)(0.f), 0, 0, 0);
            int col = (u - 4) * 16 + bl;
            gtile[(eb + 0) * 34 + col] = (_Float16)dd[0];
            gtile[(eb + 1) * 34 + col] = (_Float16)dd[1];
            gtile[(eb + 2) * 34 + col] = (_Float16)dd[2];
            gtile[(eb + 3) * 34 + col] = (_Float16)dd[3];
        }
    }
    {
        const uint* growB = (const uint*)(wbase + (size_t)lane * 68);
        uint hp[16];
#pragma unroll
        for (int q = 0; q < 16; q++) {
            half2_t gg = __builtin_bit_cast(half2_t, growB[q]);
            half2_t v;
            v.x = (_Float16)silu_f((float)gg.x + b1[2 * q + 0]);
            v.y = (_Float16)silu_f((float)gg.y + b1[2 * q + 1]);
            hp[q] = __builtin_bit_cast(uint, v);
        }
        uint4* hrow4 = (uint4*)(hbufp + (size_t)i * 16);
#pragma unroll
        for (int q = 0; q < 4; q++)
            hrow4[q] = make_uint4(hp[4 * q + 0], hp[4 * q + 1], hp[4 * q + 2], hp[4 * q + 3]);
    }

    // ---- phase A: att filter cols 0..63 into stride-66 tile (same buffer) ----
    // afr/bfr have their LAST use here -> dead before the logit chain.
#pragma unroll
    for (int t = 0; t < 4; t++) {
        half8_t av = __builtin_bit_cast(half8_t, afr[t]);
        int eb = t * 16 + bq * 4;
#pragma unroll
        for (int u = 0; u < 4; u++) {
            float4_t dd = __builtin_amdgcn_mfma_f32_16x16x32_f16(
                av, __builtin_bit_cast(half8_t, bfr[u]), (float4_t)(0.f), 0, 0, 0);
            int col = u * 16 + bl;
            gtile[(eb + 0) * 66 + col] = (_Float16)dd[0];
            gtile[(eb + 1) * 66 + col] = (_Float16)dd[1];
            gtile[(eb + 2) * 66 + col] = (_Float16)dd[2];
            gtile[(eb + 3) * 66 + col] = (_Float16)dd[3];
        }
    }
    const uint* grow = (const uint*)(wbase + (size_t)lane * 132);

    const uint2* p1h = (const uint2*)(P1h + (size_t)dst * 64);
    const uint2* p2h = (const uint2*)(P2h + (size_t)src * 64);
    float logit = ba2[0];
#pragma unroll
    for (int q = 0; q < 16; q++) {
        uint2 ua = p1h[q];
        uint2 ub = p2h[q];
        half2_t s01 = __builtin_bit_cast(half2_t, ua.x) + __builtin_bit_cast(half2_t, ub.x)
                    + __builtin_bit_cast(half2_t, grow[2 * q + 0]);
        half2_t s23 = __builtin_bit_cast(half2_t, ua.y) + __builtin_bit_cast(half2_t, ub.y)
                    + __builtin_bit_cast(half2_t, grow[2 * q + 1]);
        logit = fmaf(silu_f((float)s01.x), Wa2[4 * q + 0], logit);
        logit = fmaf(silu_f((float)s01.y), Wa2[4 * q + 1], logit);
        logit = fmaf(silu_f((float)s23.x), Wa2[4 * q + 2], logit);
        logit = fmaf(silu_f((float)s23.y), Wa2[4 * q + 3], logit);
    }
    float att = __fdividef(1.f, 1.f + __expf(-logit));

    attsh[i] = make_float4(att, sh0, sh1, sh2);
    srcbuf[i] = src;
}

// ================= gather: NPW nodes per wave (round-11 proven) =========
static constexpr int NPW = 5;
__global__ __launch_bounds__(256, 4) void k_gather_mfma(
    const float* __restrict__ scalars, const float* __restrict__ vectors,
    const _Float16* __restrict__ sc16p, const _Float16* __restrict__ vec16p,
    const float* __restrict__ b2,
    const int* __restrict__ row_start,
    const float4* __restrict__ attsh, const int* __restrict__ srcbuf,
    const uint* __restrict__ hbuf, const uint* __restrict__ tbl2,
    float* __restrict__ out)
{
    int wid  = threadIdx.x >> 6;
    int lane = threadIdx.x & 63;
    int gw   = blockIdx.x * 4 + wid;      // 2000*4 = 8000 waves
    int bl = lane & 15, bq = lane >> 4;

    uint4 bfr2[6];
#pragma unroll
    for (int u = 0; u < 6; u++)
        bfr2[u] = *(const uint4*)(tbl2 + (u * 16 + bl) * 16 + bq * 4);

    float b2s[4];
#pragma unroll
    for (int u = 0; u < 4; u++) b2s[u] = b2[u * 16 + bl];
    float bvf = b2[64 + bl], bvg = b2[80 + bl];

    int n0 = gw * NPW;
    for (int nn = 0; nn < NPW; nn++) {
        int n = n0 + nn;
        int rs = rfl(row_start[n]);
        int re = rfl(row_start[n + 1]);

        float accS0 = 0.f, accS1 = 0.f, accS2 = 0.f, accS3 = 0.f;
        float accV0 = 0.f, accV1 = 0.f, accV2 = 0.f;

        for (int i0 = rs; i0 < re; i0 += 16) {
            uint4 av4 = make_uint4(0u, 0u, 0u, 0u);
            if (i0 + bl < re)
                av4 = *(const uint4*)(hbuf + (size_t)(i0 + bl) * 16 + bq * 4);
            half8_t av = __builtin_bit_cast(half8_t, av4);

            float4_t d0 = __builtin_amdgcn_mfma_f32_16x16x32_f16(av, __builtin_bit_cast(half8_t, bfr2[0]), (float4_t)(0.f), 0, 0, 0);
            float4_t d1 = __builtin_amdgcn_mfma_f32_16x16x32_f16(av, __builtin_bit_cast(half8_t, bfr2[1]), (float4_t)(0.f), 0, 0, 0);
            float4_t d2 = __builtin_amdgcn_mfma_f32_16x16x32_f16(av, __builtin_bit_cast(half8_t, bfr2[2]), (float4_t)(0.f), 0, 0, 0);
            float4_t d3 = __builtin_amdgcn_mfma_f32_16x16x32_f16(av, __builtin_bit_cast(half8_t, bfr2[3]), (float4_t)(0.f), 0, 0, 0);
            float4_t d4 = __builtin_amdgcn_mfma_f32_16x16x32_f16(av, __builtin_bit_cast(half8_t, bfr2[4]), (float4_t)(0.f), 0, 0, 0);
            float4_t d5 = __builtin_amdgcn_mfma_f32_16x16x32_f16(av, __builtin_bit_cast(half8_t, bfr2[5]), (float4_t)(0.f), 0, 0, 0);

#pragma unroll
            for (int r = 0; r < 4; r++) {
                int slot = i0 + bq * 4 + r;
                int ok = (slot < re);
                int cs = ok ? slot : (re - 1);
                float4 as = attsh[cs];
                float att = ok ? as.x : 0.f;
                int src = srcbuf[cs];
                uint2 su = *(const uint2*)(sc16p + (size_t)src * 64 + bl * 4);
                uint2 vu = *(const uint2*)(vec16p + (size_t)src * 64 + bl * 4);
                half2_t s01 = __builtin_bit_cast(half2_t, su.x);
                half2_t s23 = __builtin_bit_cast(half2_t, su.y);
                half2_t v01 = __builtin_bit_cast(half2_t, vu.x);
                half2_t v23 = __builtin_bit_cast(half2_t, vu.y);
                accS0 = fmaf(att * (float)s01.x, d0[r] + b2s[0], accS0);
                accS1 = fmaf(att * (float)s01.y, d1[r] + b2s[1], accS1);
                accS2 = fmaf(att * (float)s23.x, d2[r] + b2s[2], accS2);
                accS3 = fmaf(att * (float)s23.y, d3[r] + b2s[3], accS3);
                float vf = d4[r] + bvf;
                float vg = d5[r] + bvg;
                accV0 = fmaf(att, fmaf((float)v01.x, vf, vg * as.y), accV0);
                accV1 = fmaf(att, fmaf((float)v01.y, vf, vg * as.z), accV1);
                accV2 = fmaf(att, fmaf((float)v23.x, vf, vg * as.w), accV2);
            }
        }

        accS0 += __shfl_xor(accS0, 16, 64); accS0 += __shfl_xor(accS0, 32, 64);
        accS1 += __shfl_xor(accS1, 16, 64); accS1 += __shfl_xor(accS1, 32, 64);
        accS2 += __shfl_xor(accS2, 16, 64); accS2 += __shfl_xor(accS2, 32, 64);
        accS3 += __shfl_xor(accS3, 16, 64); accS3 += __shfl_xor(accS3, 32, 64);
        accV0 += __shfl_xor(accV0, 16, 64); accV0 += __shfl_xor(accV0, 32, 64);
        accV1 += __shfl_xor(accV1, 16, 64); accV1 += __shfl_xor(accV1, 32, 64);
        accV2 += __shfl_xor(accV2, 16, 64); accV2 += __shfl_xor(accV2, 32, 64);

        if (bq == 0) {
            size_t o = (size_t)n * 64 + bl;
            out[o +  0] = scalars[o +  0] + accS0;
            out[o + 16] = scalars[o + 16] + accS1;
            out[o + 32] = scalars[o + 32] + accS2;
            out[o + 48] = scalars[o + 48] + accS3;
            size_t ov = (size_t)n * 48 + 3 * bl;
            out[NS + ov + 0] = vectors[ov + 0] + accV0;
            out[NS + ov + 1] = vectors[ov + 1] + accV1;
            out[NS + ov + 2] = vectors[ov + 2] + accV2;
        }
    }
}

extern "C" void kernel_launch(void* const* d_in, const int* in_sizes, int n_in,
                              void* d_out, int out_size, void* d_ws, size_t ws_size,
                              hipStream_t stream)
{
    const float* scalars  = (const float*)d_in[0];
    const float* vectors  = (const float*)d_in[1];
    const float* edge_vec = (const float*)d_in[2];
    const float* W1  = (const float*)d_in[3];
    const float* b1  = (const float*)d_in[4];
    const float* W2  = (const float*)d_in[5];
    const float* b2  = (const float*)d_in[6];
    const float* Wa1 = (const float*)d_in[7];
    const float* ba1 = (const float*)d_in[8];
    const float* Wa2 = (const float*)d_in[9];
    const float* ba2 = (const float*)d_in[10];
    const int* eidx  = (const int*)d_in[11];

    char* wsb = (char*)d_ws;
    // round-17 proven layout:
    // region used: hbuf 81.92 + tbls 0.01 + P1h/P2h/sc16p 15.36 + rec 20.48
    // + cntB 6.4 = 124.2MB < 163.84MB reserved. vec16p (5.12MB) in dead P1.
    float4* attsh = (float4*)wsb;                       // E float4
    float*  P1    = (float*)(wsb + (size_t)E_ * 16);    // NS floats (dead -> vec16p)
    float*  P2    = P1 + NS;                            // NS floats (dead)
    float*  hbuf  = P2 + NS;                            // region start: 32E floats
    int* cnt       = (int*)(hbuf + (size_t)32 * E_);    // N (unused legacy)
    int* bsum      = cnt + N_;                          // 40
    int* row_start = cnt + 2 * N_;                      // N+1
    int* perm      = row_start + N_ + 1;                // E (dead)
    int* srcbuf    = perm + E_;                         // E (written by k_edges)
    int*  rloc = (int*)hbuf;                            // aliases hbuf head (dead after k_place3b)
    uint* tbl  = (uint*)hbuf + (size_t)16 * E_;         // 1536
    uint* tbl2 = tbl + 1536;                            // 1536
    _Float16* P1h  = (_Float16*)(tbl2 + 1536);          // NS halves
    _Float16* P2h  = P1h + NS;                          // NS halves
    _Float16* sc16p = P2h + NS;                         // NS halves (permuted order)
    _Float16* vec16p = (_Float16*)P1;                   // N*64 halves (permuted+padded)
    float4* rec = (float4*)(sc16p + NS);                // E float4 (packed edge records)
    int* cntB   = (int*)(rec + E_);                     // HB*N_ ints (per-block counts)

    k_hist<<<HB, 1024, 0, stream>>>(eidx, cntB, rloc);
    k_scanB<<<40, 1024, 0, stream>>>(cntB, row_start, bsum);
    k_scan3<<<40, 1024, 0, stream>>>(bsum, row_start);
    k_place3b<<<5000, 256, 0, stream>>>(eidx, edge_vec, row_start, cntB, rloc, rec);
    k_patt<<<PATT_BLOCKS, 256, 0, stream>>>(scalars, Wa1, ba1, P1h, P2h);
    k_convp<<<5012, 256, 0, stream>>>(scalars, vectors, sc16p, vec16p, W1, Wa1, W2, tbl, tbl2);
    k_edges_sorted<<<5000, 256, 0, stream>>>(rec, P1h, P2h,
                                             tbl, b1, Wa2, ba2,
                                             attsh, srcbuf, (uint*)hbuf);
    k_gather_mfma<<<2000, 256, 0, stream>>>(scalars, vectors, sc16p, vec16p, b2, row_start,
                                            attsh, srcbuf, (const uint*)hbuf, tbl2,
                                            (float*)d_out);
}

// Round 19
// 338.437 us; speedup vs baseline: 1.1482x; 1.0253x over previous
//
#include <hip/hip_runtime.h>

static constexpr int N_ = 40000;
static constexpr int E_ = 1280000;
static constexpr int NS = N_ * 64;      // 2,560,000 scalar elems
static constexpr int NV = N_ * 48;      // 1,920,000 vector elems
static constexpr int HB = 40;           // histogram blocks
static constexpr int CHUNK = E_ / HB;   // 32000 edges per block

typedef _Float16 half2_t __attribute__((ext_vector_type(2)));
typedef _Float16 half8_t __attribute__((ext_vector_type(8)));
typedef float float4_t __attribute__((ext_vector_type(4)));
typedef unsigned int uint;
typedef unsigned short ushort_t;

__device__ __forceinline__ float silu_f(float x) { return __fdividef(x, 1.f + __expf(-x)); }
__device__ __forceinline__ int rfl(int x) { return __builtin_amdgcn_readfirstlane(x); }

// ============ rank WITHOUT global atomics: block-local LDS histogram ==========
// (round-17 proven)
__global__ __launch_bounds__(1024) void k_hist(
    const int* __restrict__ eidx, int* __restrict__ cntB, int* __restrict__ rloc)
{
    __shared__ int bins[N_];               // 156.25 KB
    int b = blockIdx.x, tid = threadIdx.x;
    for (int j = tid; j < N_; j += 1024) bins[j] = 0;
    __syncthreads();
    int e0 = b * CHUNK;
    for (int e = e0 + tid; e < e0 + CHUNK; e += 1024)
        rloc[e] = atomicAdd(&bins[eidx[E_ + e]], 1);
    __syncthreads();
    for (int j = tid; j < N_; j += 1024) cntB[b * N_ + j] = bins[j];   // coalesced dump
}

// ====== scanB: in-place exclusive prefix over blocks per dst + node totals ====
__global__ void k_scanB(int* __restrict__ cntB, int* __restrict__ row_start,
                        int* __restrict__ bsum)
{
    __shared__ int buf[1024];
    int b = blockIdx.x, tid = threadIdx.x;
    int idx = b * 1024 + tid;
    int v = 0;
    if (idx < N_) {
        for (int c = 0; c < HB; c++) {
            int t = cntB[c * N_ + idx];
            cntB[c * N_ + idx] = v;        // exclusive prefix over blocks
            v += t;
        }
    }
    buf[tid] = v;
    __syncthreads();
    for (int off = 1; off < 1024; off <<= 1) {
        int t = (tid >= off) ? buf[tid - off] : 0;
        __syncthreads();
        buf[tid] += t;
        __syncthreads();
    }
    if (idx < N_) row_start[idx] = buf[tid] - v;
    if (tid == 1023) bsum[b] = buf[1023];
}

// fused scan2+scan3: each block serially sums bsum[0..b-1] (<=40 ints)
__global__ void k_scan3(const int* __restrict__ bsum, int* __restrict__ row_start)
{
    __shared__ int boffs;
    if (threadIdx.x == 0) {
        int s = 0;
        for (int b = 0; b < (int)blockIdx.x; b++) s += bsum[b];
        boffs = s;
    }
    __syncthreads();
    int idx = blockIdx.x * 1024 + threadIdx.x;
    if (idx < N_) row_start[idx] += boffs;
    if (idx == N_) row_start[N_] = E_;
}

// place ONE 16B record per edge into sorted slot (round-12 proven store shape):
// slot = row_start[dst] + cntB[e/CHUNK][dst] + rloc[e].
__global__ void k_place3b(const int* __restrict__ eidx, const float* __restrict__ edge_vec,
                          const int* __restrict__ row_start, const int* __restrict__ cntB,
                          const int* __restrict__ rloc, float4* __restrict__ rec)
{
    int e = blockIdx.x * 256 + threadIdx.x;
    int src = eidx[e];
    int dst = eidx[E_ + e];
    int b = e / CHUNK;
    size_t slot = (size_t)(row_start[dst] + cntB[b * N_ + dst] + rloc[e]);
    uint sd = (uint)src | ((uint)dst << 16);
    rec[slot] = make_float4(edge_vec[3 * e + 0], edge_vec[3 * e + 1],
                            edge_vec[3 * e + 2], __uint_as_float(sd));
}

// ============ fused prep: convp+pack | patt (block ranges) ====================
// bounds(256,1): allocator unconstrained -> patt's w[128] cannot spill (the
// r14 failure was a 128-VGPR clamp). convp is BW-bound, tolerates high alloc.
// patt uses virtual block id -> arithmetic bit-identical to standalone.
static constexpr int PATT_BLOCKS = 512;              // 2048 waves
__global__ __launch_bounds__(256, 1) void k_prep2(
    const float* __restrict__ scalars, const float* __restrict__ vectors,
    _Float16* __restrict__ sc16p, _Float16* __restrict__ vec16p,
    const float* __restrict__ W1, const float* __restrict__ Wa1,
    const float* __restrict__ ba1, const float* __restrict__ W2,
    uint* __restrict__ tbl, uint* __restrict__ tbl2,
    _Float16* __restrict__ P1h, _Float16* __restrict__ P2h)
{
    int bid = blockIdx.x;
    if (bid < 5012) {
        if (bid >= 5000) {                 // pack (12 blocks)
            int t = (bid - 5000) * 256 + threadIdx.x;
            if (t < 1536) {
                int j = t >> 4, q = t & 15;
                int k0 = 2 * q, k1 = 2 * q + 1;
                float a = (j < 64) ? Wa1[(128 + k0) * 64 + j] : W1[k0 * 32 + (j - 64)];
                float b = (j < 64) ? Wa1[(128 + k1) * 64 + j] : W1[k1 * 32 + (j - 64)];
                half2_t v; v.x = (_Float16)a; v.y = (_Float16)b;
                tbl[t] = __builtin_bit_cast(uint, v);
            } else if (t < 3072) {
                int tt = t - 1536;
                int j = tt >> 4, q = tt & 15;
                half2_t v;
                v.x = (_Float16)W2[(2 * q + 0) * 96 + j];
                v.y = (_Float16)W2[(2 * q + 1) * 96 + j];
                tbl2[tt] = __builtin_bit_cast(uint, v);
            }
            return;
        }
        int t = bid * 256 + threadIdx.x;   // 5000*256 = N_*32 exactly
        if (t < N_ * 16) {
            int n = t >> 4, bl = t & 15;
            const float* srow = scalars + (size_t)n * 64;
            half2_t a, b;
            a.x = (_Float16)srow[bl];
            a.y = (_Float16)srow[16 + bl];
            b.x = (_Float16)srow[32 + bl];
            b.y = (_Float16)srow[48 + bl];
            uint2 u; u.x = __builtin_bit_cast(uint, a); u.y = __builtin_bit_cast(uint, b);
            *(uint2*)(sc16p + (size_t)n * 64 + bl * 4) = u;
        } else {
            int tt = t - N_ * 16;
            int n = tt >> 4, bl = tt & 15;
            const float* vrow = vectors + (size_t)n * 48 + bl * 3;
            half2_t a, b;
            a.x = (_Float16)vrow[0];
            a.y = (_Float16)vrow[1];
            b.x = (_Float16)vrow[2];
            b.y = (_Float16)0.f;
            uint2 u; u.x = __builtin_bit_cast(uint, a); u.y = __builtin_bit_cast(uint, b);
            *(uint2*)(vec16p + (size_t)n * 64 + bl * 4) = u;
        }
        return;
    }
    // ---- patt: per-node attention precompute, wave-resident weights ----
    int vb   = bid - 5012;                             // virtual block id 0..511
    int gw   = (vb * 256 + threadIdx.x) >> 6;          // global wave id (as r12)
    int lane = threadIdx.x & 63;
    float w[128];
#pragma unroll
    for (int k = 0; k < 128; k++) w[k] = Wa1[k * 64 + lane];
    float bias = ba1[lane];
    for (int n = gw; n < N_; n += PATT_BLOCKS * 4) {
        float sv = scalars[(size_t)n * 64 + lane];
        float a1 = bias, a2 = 0.f;
#pragma unroll
        for (int k = 0; k < 64; k++) {
            float sk = __shfl(sv, k, 64);
            a1 = fmaf(sk, w[k], a1);
            a2 = fmaf(sk, w[64 + k], a2);
        }
        P1h[(size_t)n * 64 + lane] = (_Float16)a1;
        P2h[(size_t)n * 64 + lane] = (_Float16)a2;
    }
}

// ================= edge phase: r18 body; attsh+srcbuf merged into ONE meta ====
// meta = {att f32, sh0 f32, sh1 f32, (f16)sh2 | src<<16}: drops the 4B srcbuf
// scattered store (edges) and one broadcast load per r-step (gather).
__global__ __launch_bounds__(256, 4) void k_edges_sorted(
    const float4* __restrict__ rec,
    const _Float16* __restrict__ P1h, const _Float16* __restrict__ P2h,
    const uint* __restrict__ tbl, const float* __restrict__ b1,
    const float* __restrict__ Wa2, const float* __restrict__ ba2,
    float4* __restrict__ attsh, uint* __restrict__ hbufp)
{
    __shared__ char lds_raw[4 * 8448];
    int tid = threadIdx.x;
    int wid = tid >> 6, lane = tid & 63;
    char* wbase = lds_raw + wid * 8448;
    int bl = lane & 15, bq = lane >> 4;

    int i = blockIdx.x * 256 + tid;        // i IS the sorted slot
    float4 ra = rec[(size_t)i];
    float ev0 = ra.x, ev1 = ra.y, ev2 = ra.z;
    uint sd = __float_as_uint(ra.w);
    int src = (int)(sd & 0xffffu);
    int dst = (int)(sd >> 16);

    float d = sqrtf(fmaf(ev0, ev0, fmaf(ev1, ev1, ev2 * ev2)));
    float inv_d = __fdividef(1.f, fmaxf(d, 1e-8f));
    float cut = (d < 10.f) ? 0.5f * (__cosf(0.31415927f * d) + 1.f) : 0.f;
    float cutd = cut * inv_d;
    float sh0 = ev1 * inv_d, sh1 = ev2 * inv_d, sh2 = ev0 * inv_d;

    // rbf via sin recurrence: sin((k+1)t) = 2cos(t)sin(kt) - sin((k-1)t)
    float th = 0.31415927f * d;
    float scur = __sinf(th);
    float twoC = 2.f * __cosf(th);
    float sprev = 0.f;
    uint rbf2[16];
#pragma unroll
    for (int q = 0; q < 16; q++) {
        float r0 = scur * cutd;
        float snext = fmaf(twoC, scur, -sprev);
        sprev = scur; scur = snext;
        float r1 = scur * cutd;
        snext = fmaf(twoC, scur, -sprev);
        sprev = scur; scur = snext;
        half2_t v; v.x = (_Float16)r0; v.y = (_Float16)r1;
        rbf2[q] = __builtin_bit_cast(uint, v);
    }
    {
        uint4* rw = (uint4*)(wbase + lane * 64);
        rw[0] = make_uint4(rbf2[0], rbf2[1], rbf2[2], rbf2[3]);
        rw[1] = make_uint4(rbf2[4], rbf2[5], rbf2[6], rbf2[7]);
        rw[2] = make_uint4(rbf2[8], rbf2[9], rbf2[10], rbf2[11]);
        rw[3] = make_uint4(rbf2[12], rbf2[13], rbf2[14], rbf2[15]);
    }
    uint4 bfr[6];
#pragma unroll
    for (int u = 0; u < 6; u++)
        bfr[u] = *(const uint4*)(tbl + (u * 16 + bl) * 16 + bq * 4);

    uint4 afr[4];
#pragma unroll
    for (int t = 0; t < 4; t++)
        afr[t] = *(const uint4*)(wbase + (t * 16 + bl) * 64 + bq * 16);

    _Float16* gtile = (_Float16*)wbase;

    // ---- phase H (FIRST): h filter cols 0..31 into stride-34 tile ----
#pragma unroll
    for (int t = 0; t < 4; t++) {
        half8_t av = __builtin_bit_cast(half8_t, afr[t]);
        int eb = t * 16 + bq * 4;
#pragma unroll
        for (int u = 4; u < 6; u++) {
            float4_t dd = __builtin_amdgcn_mfma_f32_16x16x32_f16(
                av, __builtin_bit_cast(half8_t, bfr[u]), (float4_t)(0.f), 0, 0, 0);
            int col = (u - 4) * 16 + bl;
            gtile[(eb + 0) * 34 + col] = (_Float16)dd[0];
            gtile[(eb + 1) * 34 + col] = (_Float16)dd[1];
            gtile[(eb + 2) * 34 + col] = (_Float16)dd[2];
            gtile[(eb + 3) * 34 + col] = (_Float16)dd[3];
        }
    }
    {
        const uint* growB = (const uint*)(wbase + (size_t)lane * 68);
        uint hp[16];
#pragma unroll
        for (int q = 0; q < 16; q++) {
            half2_t gg = __builtin_bit_cast(half2_t, growB[q]);
            half2_t v;
            v.x = (_Float16)silu_f((float)gg.x + b1[2 * q + 0]);
            v.y = (_Float16)silu_f((float)gg.y + b1[2 * q + 1]);
            hp[q] = __builtin_bit_cast(uint, v);
        }
        uint4* hrow4 = (uint4*)(hbufp + (size_t)i * 16);
#pragma unroll
        for (int q = 0; q < 4; q++)
            hrow4[q] = make_uint4(hp[4 * q + 0], hp[4 * q + 1], hp[4 * q + 2], hp[4 * q + 3]);
    }

    // ---- phase A: att filter cols 0..63 into stride-66 tile (same buffer) ----
#pragma unroll
    for (int t = 0; t < 4; t++) {
        half8_t av = __builtin_bit_cast(half8_t, afr[t]);
        int eb = t * 16 + bq * 4;
#pragma unroll
        for (int u = 0; u < 4; u++) {
            float4_t dd = __builtin_amdgcn_mfma_f32_16x16x32_f16(
                av, __builtin_bit_cast(half8_t, bfr[u]), (float4_t)(0.f), 0, 0, 0);
            int col = u * 16 + bl;
            gtile[(eb + 0) * 66 + col] = (_Float16)dd[0];
            gtile[(eb + 1) * 66 + col] = (_Float16)dd[1];
            gtile[(eb + 2) * 66 + col] = (_Float16)dd[2];
            gtile[(eb + 3) * 66 + col] = (_Float16)dd[3];
        }
    }
    const uint* grow = (const uint*)(wbase + (size_t)lane * 132);

    const uint2* p1h = (const uint2*)(P1h + (size_t)dst * 64);
    const uint2* p2h = (const uint2*)(P2h + (size_t)src * 64);
    float logit = ba2[0];
#pragma unroll
    for (int q = 0; q < 16; q++) {
        uint2 ua = p1h[q];
        uint2 ub = p2h[q];
        half2_t s01 = __builtin_bit_cast(half2_t, ua.x) + __builtin_bit_cast(half2_t, ub.x)
                    + __builtin_bit_cast(half2_t, grow[2 * q + 0]);
        half2_t s23 = __builtin_bit_cast(half2_t, ua.y) + __builtin_bit_cast(half2_t, ub.y)
                    + __builtin_bit_cast(half2_t, grow[2 * q + 1]);
        logit = fmaf(silu_f((float)s01.x), Wa2[4 * q + 0], logit);
        logit = fmaf(silu_f((float)s01.y), Wa2[4 * q + 1], logit);
        logit = fmaf(silu_f((float)s23.x), Wa2[4 * q + 2], logit);
        logit = fmaf(silu_f((float)s23.y), Wa2[4 * q + 3], logit);
    }
    float att = __fdividef(1.f, 1.f + __expf(-logit));

    uint w = (uint)__builtin_bit_cast(ushort_t, (_Float16)sh2) | ((uint)src << 16);
    attsh[i] = make_float4(att, sh0, sh1, __uint_as_float(w));
}

// ================= gather: NPW nodes/wave; src+sh2 decoded from meta ==========
static constexpr int NPW = 5;
__global__ __launch_bounds__(256, 4) void k_gather_mfma(
    const float* __restrict__ scalars, const float* __restrict__ vectors,
    const _Float16* __restrict__ sc16p, const _Float16* __restrict__ vec16p,
    const float* __restrict__ b2,
    const int* __restrict__ row_start,
    const float4* __restrict__ attsh,
    const uint* __restrict__ hbuf, const uint* __restrict__ tbl2,
    float* __restrict__ out)
{
    int wid  = threadIdx.x >> 6;
    int lane = threadIdx.x & 63;
    int gw   = blockIdx.x * 4 + wid;      // 2000*4 = 8000 waves
    int bl = lane & 15, bq = lane >> 4;

    uint4 bfr2[6];
#pragma unroll
    for (int u = 0; u < 6; u++)
        bfr2[u] = *(const uint4*)(tbl2 + (u * 16 + bl) * 16 + bq * 4);

    float b2s[4];
#pragma unroll
    for (int u = 0; u < 4; u++) b2s[u] = b2[u * 16 + bl];
    float bvf = b2[64 + bl], bvg = b2[80 + bl];

    int n0 = gw * NPW;
    for (int nn = 0; nn < NPW; nn++) {
        int n = n0 + nn;
        int rs = rfl(row_start[n]);
        int re = rfl(row_start[n + 1]);

        float accS0 = 0.f, accS1 = 0.f, accS2 = 0.f, accS3 = 0.f;
        float accV0 = 0.f, accV1 = 0.f, accV2 = 0.f;

        for (int i0 = rs; i0 < re; i0 += 16) {
            uint4 av4 = make_uint4(0u, 0u, 0u, 0u);
            if (i0 + bl < re)
                av4 = *(const uint4*)(hbuf + (size_t)(i0 + bl) * 16 + bq * 4);
            half8_t av = __builtin_bit_cast(half8_t, av4);

            float4_t d0 = __builtin_amdgcn_mfma_f32_16x16x32_f16(av, __builtin_bit_cast(half8_t, bfr2[0]), (float4_t)(0.f), 0, 0, 0);
            float4_t d1 = __builtin_amdgcn_mfma_f32_16x16x32_f16(av, __builtin_bit_cast(half8_t, bfr2[1]), (float4_t)(0.f), 0, 0, 0);
            float4_t d2 = __builtin_amdgcn_mfma_f32_16x16x32_f16(av, __builtin_bit_cast(half8_t, bfr2[2]), (float4_t)(0.f), 0, 0, 0);
            float4_t d3 = __builtin_amdgcn_mfma_f32_16x16x32_f16(av, __builtin_bit_cast(half8_t, bfr2[3]), (float4_t)(0.f), 0, 0, 0);
            float4_t d4 = __builtin_amdgcn_mfma_f32_16x16x32_f16(av, __builtin_bit_cast(half8_t, bfr2[4]), (float4_t)(0.f), 0, 0, 0);
            float4_t d5 = __builtin_amdgcn_mfma_f32_16x16x32_f16(av, __builtin_bit_cast(half8_t, bfr2[5]), (float4_t)(0.f), 0, 0, 0);

#pragma unroll
            for (int r = 0; r < 4; r++) {
                int slot = i0 + bq * 4 + r;
                int ok = (slot < re);
                int cs = ok ? slot : (re - 1);
                float4 as = attsh[cs];
                uint w = __float_as_uint(as.w);
                int src = (int)(w >> 16);
                float sh2v = (float)__builtin_bit_cast(_Float16, (ushort_t)(w & 0xffffu));
                float att = ok ? as.x : 0.f;
                uint2 su = *(const uint2*)(sc16p + (size_t)src * 64 + bl * 4);
                uint2 vu = *(const uint2*)(vec16p + (size_t)src * 64 + bl * 4);
                half2_t s01 = __builtin_bit_cast(half2_t, su.x);
                half2_t s23 = __builtin_bit_cast(half2_t, su.y);
                half2_t v01 = __builtin_bit_cast(half2_t, vu.x);
                half2_t v23 = __builtin_bit_cast(half2_t, vu.y);
                accS0 = fmaf(att * (float)s01.x, d0[r] + b2s[0], accS0);
                accS1 = fmaf(att * (float)s01.y, d1[r] + b2s[1], accS1);
                accS2 = fmaf(att * (float)s23.x, d2[r] + b2s[2], accS2);
                accS3 = fmaf(att * (float)s23.y, d3[r] + b2s[3], accS3);
                float vf = d4[r] + bvf;
                float vg = d5[r] + bvg;
                accV0 = fmaf(att, fmaf((float)v01.x, vf, vg * as.y), accV0);
                accV1 = fmaf(att, fmaf((float)v01.y, vf, vg * as.z), accV1);
                accV2 = fmaf(att, fmaf((float)v23.x, vf, vg * sh2v), accV2);
            }
        }

        accS0 += __shfl_xor(accS0, 16, 64); accS0 += __shfl_xor(accS0, 32, 64);
        accS1 += __shfl_xor(accS1, 16, 64); accS1 += __shfl_xor(accS1, 32, 64);
        accS2 += __shfl_xor(accS2, 16, 64); accS2 += __shfl_xor(accS2, 32, 64);
        accS3 += __shfl_xor(accS3, 16, 64); accS3 += __shfl_xor(accS3, 32, 64);
        accV0 += __shfl_xor(accV0, 16, 64); accV0 += __shfl_xor(accV0, 32, 64);
        accV1 += __shfl_xor(accV1, 16, 64); accV1 += __shfl_xor(accV1, 32, 64);
        accV2 += __shfl_xor(accV2, 16, 64); accV2 += __shfl_xor(accV2, 32, 64);

        if (bq == 0) {
            size_t o = (size_t)n * 64 + bl;
            out[o +  0] = scalars[o +  0] + accS0;
            out[o + 16] = scalars[o + 16] + accS1;
            out[o + 32] = scalars[o + 32] + accS2;
            out[o + 48] = scalars[o + 48] + accS3;
            size_t ov = (size_t)n * 48 + 3 * bl;
            out[NS + ov + 0] = vectors[ov + 0] + accV0;
            out[NS + ov + 1] = vectors[ov + 1] + accV1;
            out[NS + ov + 2] = vectors[ov + 2] + accV2;
        }
    }
}

extern "C" void kernel_launch(void* const* d_in, const int* in_sizes, int n_in,
                              void* d_out, int out_size, void* d_ws, size_t ws_size,
                              hipStream_t stream)
{
    const float* scalars  = (const float*)d_in[0];
    const float* vectors  = (const float*)d_in[1];
    const float* edge_vec = (const float*)d_in[2];
    const float* W1  = (const float*)d_in[3];
    const float* b1  = (const float*)d_in[4];
    const float* W2  = (const float*)d_in[5];
    const float* b2  = (const float*)d_in[6];
    const float* Wa1 = (const float*)d_in[7];
    const float* ba1 = (const float*)d_in[8];
    const float* Wa2 = (const float*)d_in[9];
    const float* ba2 = (const float*)d_in[10];
    const int* eidx  = (const int*)d_in[11];

    char* wsb = (char*)d_ws;
    // round-17 proven layout (srcbuf slot now unused):
    // region used: hbuf 81.92 + tbls 0.01 + P1h/P2h/sc16p 15.36 + rec 20.48
    // + cntB 6.4 = 124.2MB < 163.84MB reserved. vec16p (5.12MB) in dead P1.
    float4* attsh = (float4*)wsb;                       // E float4 (meta records)
    float*  P1    = (float*)(wsb + (size_t)E_ * 16);    // NS floats (dead -> vec16p)
    float*  P2    = P1 + NS;                            // NS floats (dead)
    float*  hbuf  = P2 + NS;                            // region start: 32E floats
    int* cnt       = (int*)(hbuf + (size_t)32 * E_);    // N (unused legacy)
    int* bsum      = cnt + N_;                          // 40
    int* row_start = cnt + 2 * N_;                      // N+1
    int*  rloc = (int*)hbuf;                            // aliases hbuf head (dead after k_place3b)
    uint* tbl  = (uint*)hbuf + (size_t)16 * E_;         // 1536
    uint* tbl2 = tbl + 1536;                            // 1536
    _Float16* P1h  = (_Float16*)(tbl2 + 1536);          // NS halves
    _Float16* P2h  = P1h + NS;                          // NS halves
    _Float16* sc16p = P2h + NS;                         // NS halves (permuted order)
    _Float16* vec16p = (_Float16*)P1;                   // N*64 halves (permuted+padded)
    float4* rec = (float4*)(sc16p + NS);                // E float4 (packed edge records)
    int* cntB   = (int*)(rec + E_);                     // HB*N_ ints (per-block counts)

    k_hist<<<HB, 1024, 0, stream>>>(eidx, cntB, rloc);
    k_scanB<<<40, 1024, 0, stream>>>(cntB, row_start, bsum);
    k_scan3<<<40, 1024, 0, stream>>>(bsum, row_start);
    k_place3b<<<5000, 256, 0, stream>>>(eidx, edge_vec, row_start, cntB, rloc, rec);
    k_prep2<<<5524, 256, 0, stream>>>(scalars, vectors, sc16p, vec16p,
                                      W1, Wa1, ba1, W2, tbl, tbl2, P1h, P2h);
    k_edges_sorted<<<5000, 256, 0, stream>>>(rec, P1h, P2h,
                                             tbl, b1, Wa2, ba2,
                                             attsh, (uint*)hbuf);
    k_gather_mfma<<<2000, 256, 0, stream>>>(scalars, vectors, sc16p, vec16p, b2, row_start,
                                            attsh, (const uint*)hbuf, tbl2,
                                            (float*)d_out);
}